// Round 11
// baseline (417.650 us; speedup 1.0000x reference)
//
#include <hip/hip_runtime.h>
#include <hip/hip_bf16.h>
#include <math.h>

#define B_    8
#define L_    2048
#define AD    512
#define VD    512
#define H_    256
#define DIN   512
#define DSTATE 16
#define DCONV  4
#define DTRANK 16
#define NCLS   8
#define BL    (B_ * L_)   // 16384
#define NCH   128
#define CLEN  16
#define NSP   4
#define NGRP  8           // scan p2 groups (NCH/NGRP = 16 chunks each)

typedef __attribute__((ext_vector_type(8))) short bf16x8;
typedef __attribute__((ext_vector_type(4))) float f32x4;

__device__ inline bf16x8 pack8(float4 a, float4 b)
{
    bf16x8 o; __hip_bfloat16 t;
    t = __float2bfloat16(a.x); o[0] = *(short*)&t;
    t = __float2bfloat16(a.y); o[1] = *(short*)&t;
    t = __float2bfloat16(a.z); o[2] = *(short*)&t;
    t = __float2bfloat16(a.w); o[3] = *(short*)&t;
    t = __float2bfloat16(b.x); o[4] = *(short*)&t;
    t = __float2bfloat16(b.y); o[5] = *(short*)&t;
    t = __float2bfloat16(b.z); o[6] = *(short*)&t;
    t = __float2bfloat16(b.w); o[7] = *(short*)&t;
    return o;
}

// Direct global->LDS DMA, 16B per lane. LDS dest must be wave-uniform base;
// HW writes base + lane*16. Global src is per-lane (enables swizzled layouts).
__device__ __forceinline__ void gload_lds16(const void* g, void* l)
{
    __builtin_amdgcn_global_load_lds(
        (const __attribute__((address_space(1))) void*)g,
        (__attribute__((address_space(3))) void*)l,
        16, 0, 0);
}

// ---------------------------------------------------------------------------
// R11: fused cast_inputs + prep (independent work, one launch).
// blocks [0,8192): input casts. [8192,8428): weight casts.
// [8428,9452): wT transposes. [9452,9455): bias fold.
// ---------------------------------------------------------------------------
__global__ __launch_bounds__(256)
void cast_prep_kernel(const float* __restrict__ a, const float* __restrict__ v,
                      __hip_bfloat16* __restrict__ ab, __hip_bfloat16* __restrict__ vbf_,
                      const float* __restrict__ qw, const float* __restrict__ kw,
                      const float* __restrict__ vw, const float* __restrict__ ipw,
                      const float* __restrict__ xpw,
                      const float* __restrict__ aw, const float* __restrict__ vww,
                      const float* __restrict__ ab2, const float* __restrict__ vb,
                      const float* __restrict__ qb, const float* __restrict__ kb,
                      const float* __restrict__ vb2,
                      __hip_bfloat16* __restrict__ qwb, __hip_bfloat16* __restrict__ kwb,
                      __hip_bfloat16* __restrict__ vwb, __hip_bfloat16* __restrict__ ipwb,
                      __hip_bfloat16* __restrict__ xpwb,
                      __hip_bfloat16* __restrict__ awT, __hip_bfloat16* __restrict__ vwT,
                      float* __restrict__ bq, float* __restrict__ bkv)
{
    const int bx = blockIdx.x;
    if (bx < 8192) {
        size_t i = ((size_t)bx * 256 + threadIdx.x) * 8;
        const float* s; __hip_bfloat16* d; size_t off;
        if (i < 8388608) { s = a; d = ab; off = i; }
        else             { s = v; d = vbf_; off = i - 8388608; }
        float4 x = *(const float4*)(s + off);
        float4 y = *(const float4*)(s + off + 4);
        *(bf16x8*)(d + off) = pack8(x, y);
        return;
    }
    const int blk = bx - 8192;
    if (blk < 236) {
        size_t i = ((size_t)blk * 256 + threadIdx.x) * 8;
        const float* s; __hip_bfloat16* d; size_t off;
        if      (i <  65536) { s = qw;  d = qwb;  off = i; }
        else if (i < 131072) { s = kw;  d = kwb;  off = i - 65536; }
        else if (i < 196608) { s = vw;  d = vwb;  off = i - 131072; }
        else if (i < 458752) { s = ipw; d = ipwb; off = i - 196608; }
        else                 { s = xpw; d = xpwb; off = i - 458752; }
        float4 x = *(const float4*)(s + off);
        float4 y = *(const float4*)(s + off + 4);
        *(bf16x8*)(d + off) = pack8(x, y);
    } else if (blk < 1260) {
        int i = (blk - 236) * 256 + threadIdx.x;       // 0..262143
        const float* s = (i < 131072) ? aw : vww;
        __hip_bfloat16* d = (i < 131072) ? awT : vwT;
        int j = i & 131071;
        int r = j >> 9, c = j & 511;
        d[c * 256 + r] = __float2bfloat16(s[j]);
    } else {
        int seg = blk - 1260;
        int m = threadIdx.x;
        const float* w  = (seg == 0) ? qw : (seg == 1) ? kw : vw;
        const float* ib = (seg == 0) ? ab2 : vb;
        const float* ob = (seg == 0) ? qb : (seg == 1) ? kb : vb2;
        float s = ob[m];
        for (int i = 0; i < 256; ++i) s += w[m * 256 + i] * ib[i];
        if (seg == 0) bq[m] = s;
        else          bkv[(seg - 1) * 256 + m] = s;
    }
}

// ---------------------------------------------------------------------------
// Fused weight-composition GEMMs: z=0: Wq'=q_w@awT; z=1/2: Wk'/Wv'=@vwT.
// 16-row/wave, N=512, K=256, bf16 out. grid (16, 8, 3).
// ---------------------------------------------------------------------------
__global__ __launch_bounds__(64, 2)
void gemm_comp_kernel(const __hip_bfloat16* __restrict__ qw,
                      const __hip_bfloat16* __restrict__ kw,
                      const __hip_bfloat16* __restrict__ vw,
                      const __hip_bfloat16* __restrict__ awT,
                      const __hip_bfloat16* __restrict__ vwT,
                      __hip_bfloat16* __restrict__ Wqp,
                      __hip_bfloat16* __restrict__ Wkvp)
{
    const int seg = blockIdx.z;
    const __hip_bfloat16* A = (seg == 0) ? qw : (seg == 1) ? kw : vw;
    const __hip_bfloat16* W = (seg == 0) ? awT : vwT;
    __hip_bfloat16* outp = (seg == 0) ? Wqp : (Wkvp + (size_t)(seg - 1) * 256 * 512);

    const int lane = threadIdx.x;
    const int l15  = lane & 15;
    const int quad = lane >> 4;
    const int m0   = blockIdx.x * 16;
    const int n0   = blockIdx.y * 64;

    const __hip_bfloat16* Arow = A + (size_t)(m0 + l15) * 256 + quad * 8;
    f32x4 acc[4];
    #pragma unroll
    for (int nt = 0; nt < 4; ++nt) acc[nt] = (f32x4){0.f, 0.f, 0.f, 0.f};

    #pragma unroll
    for (int kc = 0; kc < 256; kc += 32) {
        bf16x8 af = *(const bf16x8*)(Arow + kc);
        #pragma unroll
        for (int nt = 0; nt < 4; ++nt) {
            bf16x8 bfv = *(const bf16x8*)(W + (size_t)(n0 + nt * 16 + l15) * 256 + kc + quad * 8);
            acc[nt] = __builtin_amdgcn_mfma_f32_16x16x32_bf16(af, bfv, acc[nt], 0, 0, 0);
        }
    }
    #pragma unroll
    for (int nt = 0; nt < 4; ++nt) {
        int col = n0 + nt * 16 + l15;
        #pragma unroll
        for (int r = 0; r < 4; ++r)
            outp[(size_t)(m0 + quad * 4 + r) * 512 + col] = __float2bfloat16(acc[nt][r]);
    }
}

// ---------------------------------------------------------------------------
// gemm4_t: 4-wave blocks, 64 rows x NT*16 cols. W staged in LDS (264-pad).
// (kept for xproj N=48)
// ---------------------------------------------------------------------------
template<int N, int K, int NT, int OBF, int ACT>
__global__ __launch_bounds__(256, 2)
void gemm4_t(const __hip_bfloat16* __restrict__ A,
             const __hip_bfloat16* __restrict__ W,
             const float* __restrict__ bias,
             void* __restrict__ outp)
{
    constexpr int NROWS = NT * 16;
    __shared__ __attribute__((aligned(16))) short Ws[NROWS * 264];
    const int tid  = threadIdx.x;
    const int lane = tid & 63;
    const int w    = tid >> 6;
    const int l15  = lane & 15;
    const int quad = lane >> 4;
    const int m0   = blockIdx.x * 64 + w * 16;
    const int n0   = blockIdx.y * 64;

    constexpr int KC = K / 32;
    bf16x8 af[KC];
    const __hip_bfloat16* Arow = A + (size_t)(m0 + l15) * K + quad * 8;
    #pragma unroll
    for (int kc = 0; kc < KC; ++kc) af[kc] = *(const bf16x8*)(Arow + kc * 32);

    f32x4 acc[NT];
    #pragma unroll
    for (int nt = 0; nt < NT; ++nt) acc[nt] = (f32x4){0.f, 0.f, 0.f, 0.f};

    #pragma unroll
    for (int kh = 0; kh < K / 256; ++kh) {
        __syncthreads();
        #pragma unroll
        for (int i = 0; i < 8; ++i) {
            int id = tid + i * 256;
            int row = id >> 5, c = id & 31;
            if (row < NROWS)
                *(bf16x8*)&Ws[row * 264 + c * 8] =
                    *(const bf16x8*)(W + (size_t)(n0 + row) * K + kh * 256 + c * 8);
        }
        __syncthreads();
        #pragma unroll
        for (int kc = 0; kc < 8; ++kc) {
            #pragma unroll
            for (int nt = 0; nt < NT; ++nt) {
                bf16x8 wv = *(const bf16x8*)&Ws[(nt * 16 + l15) * 264 + kc * 32 + quad * 8];
                acc[nt] = __builtin_amdgcn_mfma_f32_16x16x32_bf16(af[kh * 8 + kc], wv, acc[nt], 0, 0, 0);
            }
        }
    }
    #pragma unroll
    for (int nt = 0; nt < NT; ++nt) {
        int col = n0 + nt * 16 + l15;
        float bv = bias ? bias[col] : 0.f;
        #pragma unroll
        for (int r = 0; r < 4; ++r) {
            size_t idx = (size_t)(m0 + quad * 4 + r) * N + col;
            float v = acc[nt][r] + bv;
            if (ACT) v = v / (1.f + __expf(-v));
            if (OBF) ((__hip_bfloat16*)outp)[idx] = __float2bfloat16(v);
            else     ((float*)outp)[idx] = v;
        }
    }
}

// ---------------------------------------------------------------------------
// gemm8 body (R10 structure): 4-wave blocks, 128 rows x 64 cols per block,
// each wave owns TWO 16-row sets -> every LDS B-frag feeds 2 MFMAs.
// Runtime N/n0/act (block-uniform). acc order identical to gemm4_t.
// ---------------------------------------------------------------------------
template<int K>
__device__ __forceinline__ void gemm8_body(
    const __hip_bfloat16* __restrict__ A,
    const __hip_bfloat16* __restrict__ W,
    const float* __restrict__ bias,
    __hip_bfloat16* __restrict__ outp,
    int N, int n0, int act, short* Ws)
{
    constexpr int NT = 4;
    const int tid  = threadIdx.x;
    const int lane = tid & 63;
    const int w    = tid >> 6;
    const int l15  = lane & 15;
    const int quad = lane >> 4;
    const int m0   = blockIdx.x * 128 + w * 32;

    f32x4 acc[2][NT];
    #pragma unroll
    for (int s2 = 0; s2 < 2; ++s2)
        #pragma unroll
        for (int nt = 0; nt < NT; ++nt) acc[s2][nt] = (f32x4){0.f, 0.f, 0.f, 0.f};

    #pragma unroll
    for (int kh = 0; kh < K / 256; ++kh) {
        bf16x8 af[2][8];
        #pragma unroll
        for (int s2 = 0; s2 < 2; ++s2)
            #pragma unroll
            for (int kc = 0; kc < 8; ++kc)
                af[s2][kc] = *(const bf16x8*)(A + (size_t)(m0 + s2 * 16 + l15) * K
                                              + kh * 256 + kc * 32 + quad * 8);
        __syncthreads();
        #pragma unroll
        for (int i = 0; i < 8; ++i) {
            int id = tid + i * 256;
            int row = id >> 5, c = id & 31;
            *(bf16x8*)&Ws[row * 264 + c * 8] =
                *(const bf16x8*)(W + (size_t)(n0 + row) * K + kh * 256 + c * 8);
        }
        __syncthreads();
        #pragma unroll
        for (int kc = 0; kc < 8; ++kc) {
            #pragma unroll
            for (int nt = 0; nt < NT; ++nt) {
                bf16x8 wv = *(const bf16x8*)&Ws[(nt * 16 + l15) * 264 + kc * 32 + quad * 8];
                acc[0][nt] = __builtin_amdgcn_mfma_f32_16x16x32_bf16(af[0][kc], wv, acc[0][nt], 0, 0, 0);
                acc[1][nt] = __builtin_amdgcn_mfma_f32_16x16x32_bf16(af[1][kc], wv, acc[1][nt], 0, 0, 0);
            }
        }
    }
    #pragma unroll
    for (int s2 = 0; s2 < 2; ++s2)
        #pragma unroll
        for (int nt = 0; nt < NT; ++nt) {
            int col = n0 + nt * 16 + l15;
            float bv = bias ? bias[col] : 0.f;
            #pragma unroll
            for (int r = 0; r < 4; ++r) {
                size_t idx = (size_t)(m0 + s2 * 16 + quad * 4 + r) * N + col;
                float v = acc[s2][nt][r] + bv;
                if (act) v = v / (1.f + __expf(-v));
                outp[idx] = __float2bfloat16(v);
            }
        }
}

// R11: Q + KV projections in ONE launch. grid (128, 12): y<4 -> Q (N=256),
// else KV (N=512). K=512. Independent workloads; tails fill each other's CUs.
__global__ __launch_bounds__(256)
void gemm8_qkv_kernel(const __hip_bfloat16* __restrict__ abf,
                      const __hip_bfloat16* __restrict__ vbf,
                      const __hip_bfloat16* __restrict__ Wqp,
                      const __hip_bfloat16* __restrict__ Wkvp,
                      const float* __restrict__ bq,
                      const float* __restrict__ bkv,
                      __hip_bfloat16* __restrict__ Qbf,
                      __hip_bfloat16* __restrict__ KVbf)
{
    __shared__ __attribute__((aligned(16))) short Ws[64 * 264];
    const int y = blockIdx.y;
    if (y < 4)
        gemm8_body<512>(abf, Wqp,  bq,  Qbf,  256, y * 64,       0, Ws);
    else
        gemm8_body<512>(vbf, Wkvp, bkv, KVbf, 512, (y - 4) * 64, 0, Ws);
}

// R11: in_proj x + z in ONE launch. grid (128, 16): y<8 -> x (ACT=0),
// else z (ACT=1, silu). N=512, K=256.
__global__ __launch_bounds__(256)
void gemm8_xz_kernel(const __hip_bfloat16* __restrict__ fusedbf,
                     const __hip_bfloat16* __restrict__ ipwbf,
                     __hip_bfloat16* __restrict__ xbufbf,
                     __hip_bfloat16* __restrict__ zwbf)
{
    __shared__ __attribute__((aligned(16))) short Ws[64 * 264];
    const int y = blockIdx.y;
    if (y < 8)
        gemm8_body<256>(fusedbf, ipwbf,             nullptr, xbufbf, 512, y * 64,       0, Ws);
    else
        gemm8_body<256>(fusedbf, ipwbf + DIN * H_,  nullptr, zwbf,   512, (y - 8) * 64, 1, Ws);
}

// ---------------------------------------------------------------------------
// V transpose from stacked KV -> Vt[b][h][l]
// ---------------------------------------------------------------------------
__global__ __launch_bounds__(256)
void transpose_v_kernel(const __hip_bfloat16* __restrict__ KV,
                        __hip_bfloat16* __restrict__ Vt)
{
    const int tid = threadIdx.x;
    const int lc  = blockIdx.x & 7;
    const int hg  = (blockIdx.x >> 3) & 31;
    const int b   = blockIdx.x >> 8;
    const int l   = lc * 256 + tid;
    bf16x8 v = *(const bf16x8*)(KV + ((size_t)b * L_ + l) * 512 + 256 + hg * 8);
    __hip_bfloat16* dst = Vt + (size_t)b * H_ * L_ + (size_t)(hg * 8) * L_ + l;
    #pragma unroll
    for (int j = 0; j < 8; ++j) {
        short s = v[j];
        dst[(size_t)j * L_] = *(__hip_bfloat16*)&s;
    }
}

// ---------------------------------------------------------------------------
// Attention: 4 waves/block, 32 queries/WAVE, 128 q/block, 512 keys per split.
// R3: double-buffered LDS K/V staged via global_load_lds DMA (zero VGPR cost,
//     T3 2-phase). XOR chunk swizzle on global source + ds_read side.
// ---------------------------------------------------------------------------
__global__ __launch_bounds__(256, 2)
void attn_split_kernel(const __hip_bfloat16* __restrict__ Q,
                       const __hip_bfloat16* __restrict__ KV,
                       const __hip_bfloat16* __restrict__ Vt,
                       __hip_bfloat16* __restrict__ Opart,
                       float* __restrict__ lpart)
{
    __shared__ __attribute__((aligned(16))) short Ks[2][32 * 256];   // [key][256 sh], swz
    __shared__ __attribute__((aligned(16))) short Vs[2][256 * 32];   // [h][32 sh], swz
    __shared__ __attribute__((aligned(16))) short Pls[4][2][16 * 40];

    const int tid  = threadIdx.x;
    const int lane = tid & 63;
    const int w    = tid >> 6;
    const int b    = blockIdx.x & 7;
    const int qt   = (blockIdx.x >> 3) & 15;
    const int sp   = blockIdx.x >> 7;
    const int q0   = qt * 128 + w * 32;
    const int l15  = lane & 15;
    const int quad = lane >> 4;
    const int wb   = tid & 192;        // wave-uniform chunk base (w*64)

    const __hip_bfloat16* Qb = Q  + ((size_t)b * L_ + q0) * H_;
    const __hip_bfloat16* Kb = KV + (size_t)b * L_ * 512;
    const __hip_bfloat16* Vb = Vt + (size_t)b * H_ * L_;

    bf16x8 qf[2][8];
    #pragma unroll
    for (int s2 = 0; s2 < 2; ++s2)
        #pragma unroll
        for (int kc = 0; kc < 8; ++kc)
            qf[s2][kc] = *(const bf16x8*)(Qb + (size_t)(s2 * 16 + l15) * H_ + kc * 32 + quad * 8);

    f32x4 Oacc[2][16];
    #pragma unroll
    for (int s2 = 0; s2 < 2; ++s2)
        #pragma unroll
        for (int nt = 0; nt < 16; ++nt) Oacc[s2][nt] = (f32x4){0.f, 0.f, 0.f, 0.f};
    float lsum[2][4] = {{0.f,0.f,0.f,0.f},{0.f,0.f,0.f,0.f}};

    const int kbase = sp * 512;
    const int sK = l15 & 7;                       // K read swizzle (row&7)
    const int vcol8 = (quad ^ (l15 & 3)) * 8;     // V read swizzle (row&3)

    // DMA staging: 1024 chunks of 16B each for K and V per tile.
#define STAGE(KsD, VsD, stv) do {                                                 \
        const int kb_ = kbase + (stv) * 32;                                       \
        _Pragma("unroll")                                                         \
        for (int i_ = 0; i_ < 4; ++i_) {                                          \
            int q_ = i_ * 256 + tid;                                              \
            int rK_ = q_ >> 5, cK_ = q_ & 31;                                     \
            gload_lds16(Kb + (size_t)(kb_ + rK_) * 512 + ((cK_ ^ (rK_ & 7)) << 3),\
                        (KsD) + (i_ * 256 + wb) * 8);                             \
            int rV_ = q_ >> 2, cV_ = q_ & 3;                                      \
            gload_lds16(Vb + (size_t)rV_ * L_ + kb_ + ((cV_ ^ (rV_ & 3)) << 3),   \
                        (VsD) + (i_ * 256 + wb) * 8);                             \
        }                                                                         \
    } while (0)

    STAGE(Ks[0], Vs[0], 0);
    __syncthreads();                               // vmcnt(0): tile 0 landed
    for (int st = 0; st < 16; ++st) {
        const int cur = st & 1;
        short* KsC = Ks[cur];
        short* VsC = Vs[cur];
        if (st < 15) STAGE(Ks[cur ^ 1], Vs[cur ^ 1], st + 1);  // async, drains at bottom barrier
        // ---- S = Q K^T : each K-frag feeds both q-sets
        #pragma unroll
        for (int nt = 0; nt < 2; ++nt) {
            f32x4 S0 = (f32x4){0.f,0.f,0.f,0.f};
            f32x4 S1 = (f32x4){0.f,0.f,0.f,0.f};
            __builtin_amdgcn_s_setprio(1);
            #pragma unroll
            for (int kc = 0; kc < 8; ++kc) {
                bf16x8 bk = *(const bf16x8*)&KsC[(nt * 16 + l15) * 256 + (((kc * 4 + quad) ^ sK) << 3)];
                S0 = __builtin_amdgcn_mfma_f32_16x16x32_bf16(qf[0][kc], bk, S0, 0, 0, 0);
                S1 = __builtin_amdgcn_mfma_f32_16x16x32_bf16(qf[1][kc], bk, S1, 0, 0, 0);
            }
            __builtin_amdgcn_s_setprio(0);
            #pragma unroll
            for (int r = 0; r < 4; ++r) {
                float p0 = __expf(S0[r] * 0.0625f);
                float p1 = __expf(S1[r] * 0.0625f);
                lsum[0][r] += p0;
                lsum[1][r] += p1;
                __hip_bfloat16 pb0 = __float2bfloat16(p0);
                __hip_bfloat16 pb1 = __float2bfloat16(p1);
                Pls[w][0][(quad * 4 + r) * 40 + nt * 16 + l15] = *(short*)&pb0;
                Pls[w][1][(quad * 4 + r) * 40 + nt * 16 + l15] = *(short*)&pb1;
            }
        }
        bf16x8 pf0 = *(const bf16x8*)&Pls[w][0][l15 * 40 + quad * 8];
        bf16x8 pf1 = *(const bf16x8*)&Pls[w][1][l15 * 40 + quad * 8];
        // ---- O += P V : each V-frag feeds both q-sets
        __builtin_amdgcn_s_setprio(1);
        #pragma unroll
        for (int nt = 0; nt < 16; ++nt) {
            bf16x8 vf = *(const bf16x8*)&VsC[(nt * 16 + l15) * 32 + vcol8];
            Oacc[0][nt] = __builtin_amdgcn_mfma_f32_16x16x32_bf16(pf0, vf, Oacc[0][nt], 0, 0, 0);
            Oacc[1][nt] = __builtin_amdgcn_mfma_f32_16x16x32_bf16(pf1, vf, Oacc[1][nt], 0, 0, 0);
        }
        __builtin_amdgcn_s_setprio(0);
        __syncthreads();    // compute(cur) done + next tile's DMA drained (vmcnt 0)
    }
#undef STAGE
    #pragma unroll
    for (int s2 = 0; s2 < 2; ++s2)
        #pragma unroll
        for (int r = 0; r < 4; ++r) {
            lsum[s2][r] += __shfl_xor(lsum[s2][r], 1, 64);
            lsum[s2][r] += __shfl_xor(lsum[s2][r], 2, 64);
            lsum[s2][r] += __shfl_xor(lsum[s2][r], 4, 64);
            lsum[s2][r] += __shfl_xor(lsum[s2][r], 8, 64);
        }
    __hip_bfloat16* Ob = Opart + (((size_t)sp * B_ + b) * L_ + q0) * H_;
    #pragma unroll
    for (int s2 = 0; s2 < 2; ++s2)
        #pragma unroll
        for (int r = 0; r < 4; ++r)
            #pragma unroll
            for (int nt = 0; nt < 16; ++nt)
                Ob[(size_t)(s2 * 16 + quad * 4 + r) * H_ + nt * 16 + l15] =
                    __float2bfloat16(Oacc[s2][nt][r]);
    if (l15 == 0) {
        #pragma unroll
        for (int s2 = 0; s2 < 2; ++s2)
            #pragma unroll
            for (int r = 0; r < 4; ++r)
                lpart[((size_t)sp * B_ + b) * L_ + q0 + s2 * 16 + quad * 4 + r] = lsum[s2][r];
    }
}

// ---------------------------------------------------------------------------
// Merge attention splits. R7: bf16x8-vectorized. grid 2048.
// ---------------------------------------------------------------------------
__global__ __launch_bounds__(256)
void attn_merge_kernel(const __hip_bfloat16* __restrict__ Opart,
                       const float* __restrict__ lpart,
                       __hip_bfloat16* __restrict__ O)
{
    const size_t i8  = ((size_t)blockIdx.x * 256 + threadIdx.x) * 8;
    const size_t row = i8 >> 8;
    float l = 0.f;
    #pragma unroll
    for (int sp = 0; sp < NSP; ++sp) l += lpart[(size_t)sp * BL + row];
    const float inv = 1.f / l;
    float o[8] = {0.f,0.f,0.f,0.f,0.f,0.f,0.f,0.f};
    #pragma unroll
    for (int sp = 0; sp < NSP; ++sp) {
        bf16x8 v = *(const bf16x8*)(Opart + (size_t)sp * BL * H_ + i8);
        #pragma unroll
        for (int j = 0; j < 8; ++j) {
            short s = v[j];
            o[j] += __bfloat162float(*(__hip_bfloat16*)&s);
        }
    }
    bf16x8 ov;
    #pragma unroll
    for (int j = 0; j < 8; ++j) {
        __hip_bfloat16 t = __float2bfloat16(o[j] * inv);
        ov[j] = *(short*)&t;
    }
    *(bf16x8*)(O + i8) = ov;
}

// ---------------------------------------------------------------------------
// Depthwise causal conv (k=4) + bias + silu: bf16 in, bf16 out.
// R7: 8 channels/thread, bf16x8 tap loads + bf16x8 store. grid 4096.
// ---------------------------------------------------------------------------
__global__ __launch_bounds__(256)
void conv_silu_kernel(const __hip_bfloat16* __restrict__ xb,
                      const float* __restrict__ cw,
                      const float* __restrict__ cb,
                      __hip_bfloat16* __restrict__ xconvbf)
{
    const int idx = blockIdx.x * 256 + threadIdx.x;   // [0, BL*DIN/8)
    const int d0 = (idx & 63) << 3;
    const int l  = (idx >> 6) & (L_ - 1);
    const int b  = idx >> 17;

    float4 wv[8];
    float acc[8];
    #pragma unroll
    for (int j = 0; j < 8; ++j) {
        wv[j]  = *(const float4*)(cw + (d0 + j) * DCONV);
        acc[j] = cb[d0 + j];
    }
    #pragma unroll
    for (int t = 0; t < DCONV; ++t) {
        int ls = l - (DCONV - 1) + t;
        if (ls >= 0) {
            bf16x8 x = *(const bf16x8*)(xb + ((size_t)b * L_ + ls) * DIN + d0);
            #pragma unroll
            for (int j = 0; j < 8; ++j) {
                short s = x[j];
                float xv = __bfloat162float(*(__hip_bfloat16*)&s);
                float wt = (t == 0) ? wv[j].x : (t == 1) ? wv[j].y : (t == 2) ? wv[j].z : wv[j].w;
                acc[j] += xv * wt;
            }
        }
    }
    bf16x8 ov;
    #pragma unroll
    for (int j = 0; j < 8; ++j) {
        float v = acc[j] / (1.f + __expf(-acc[j]));
        __hip_bfloat16 t = __float2bfloat16(v);
        ov[j] = *(short*)&t;
    }
    *(bf16x8*)(xconvbf + (size_t)idx * 8) = ov;
}

// ---------------------------------------------------------------------------
// Merged scan phase 1. R9: dbc read via uniform s_loads (SGPRs), no LDS.
// NCH=128/CLEN=16 + sumdt (no aprod).
// ---------------------------------------------------------------------------
__global__ __launch_bounds__(256)
void scan_p1_kernel(const __hip_bfloat16* __restrict__ xconv,
                    const __hip_bfloat16* __restrict__ zw,
                    const float* __restrict__ dbc,
                    const float* __restrict__ dtw,
                    const float* __restrict__ dtbias,
                    const float* __restrict__ A_log,
                    const float* __restrict__ Dv,
                    float* __restrict__ hend,
                    float* __restrict__ sumdt,
                    float* __restrict__ Gbuf,
                    float* __restrict__ accloc)
{
    const int tid  = threadIdx.x;
    const int dgrp = blockIdx.x & 1;
    const int c    = (blockIdx.x >> 1) & (NCH - 1);
    const int b    = blockIdx.x >> 8;
    const int d    = dgrp * 256 + tid;
    const size_t rbase = (size_t)b * L_ + c * CLEN;

    float wr[16];
    #pragma unroll
    for (int r = 0; r < 16; ++r) wr[r] = dtw[d * DTRANK + r];
    const float dbias = dtbias[d];
    const float Dval  = Dv[d];

    float Aa[16];
    bool fast = true;
    #pragma unroll
    for (int s = 0; s < 16; ++s) {
        Aa[s] = -__expf(A_log[d * DSTATE + s]);
        fast = fast && (fabsf(Aa[s] + (float)(s + 1)) < 1e-3f);
    }

    float h[16], ap[16], g[16];
    #pragma unroll
    for (int s = 0; s < 16; ++s) { h[s] = 0.f; ap[s] = 1.f; g[s] = 0.f; }
    float acc = 0.f;
    float dts = 0.f;

    if (fast) {
        for (int t = 0; t < CLEN; ++t) {
            const float* __restrict__ row = dbc + (rbase + t) * 48;   // block-uniform
            float4 D0 = *(const float4*)(row);
            float4 D1 = *(const float4*)(row + 4);
            float4 D2 = *(const float4*)(row + 8);
            float4 D3 = *(const float4*)(row + 12);
            float4 B0 = *(const float4*)(row + 16);
            float4 B1 = *(const float4*)(row + 20);
            float4 B2 = *(const float4*)(row + 24);
            float4 B3 = *(const float4*)(row + 28);
            float4 C0 = *(const float4*)(row + 32);
            float4 C1 = *(const float4*)(row + 36);
            float4 C2 = *(const float4*)(row + 40);
            float4 C3 = *(const float4*)(row + 44);
            float Bv[16], Cv[16];
            *(float4*)&Bv[0] = B0; *(float4*)&Bv[4] = B1; *(float4*)&Bv[8] = B2; *(float4*)&Bv[12] = B3;
            *(float4*)&Cv[0] = C0; *(float4*)&Cv[4] = C1; *(float4*)&Cv[8] = C2; *(float4*)&Cv[12] = C3;
            float a0 = dbias + D0.x*wr[0] + D0.y*wr[1] + D0.z*wr[2] + D0.w*wr[3];
            float a1 = D1.x*wr[4] + D1.y*wr[5] + D1.z*wr[6] + D1.w*wr[7];
            float a2 = D2.x*wr[8] + D2.y*wr[9] + D2.z*wr[10] + D2.w*wr[11];
            float a3 = D3.x*wr[12] + D3.y*wr[13] + D3.z*wr[14] + D3.w*wr[15];
            float dot = (a0 + a1) + (a2 + a3);
            float dtv = (dot > 20.f) ? dot : __logf(1.f + __expf(dot));
            float xv  = __bfloat162float(xconv[(rbase + t) * DIN + d]);
            float wt  = __bfloat162float(zw   [(rbase + t) * DIN + d]);
            float u  = dtv * xv;
            float e1 = __expf(-dtv);
            float ep = 1.f;
            dts += dtv;
            #pragma unroll
            for (int s = 0; s < 16; ++s) {
                ep *= e1;
                ap[s] *= ep;
                h[s] = ep * h[s] + u * Bv[s];
                float tc = wt * Cv[s];
                acc += tc * h[s];
                g[s] += tc * ap[s];
            }
            acc += wt * xv * Dval;
        }
    } else {
        for (int t = 0; t < CLEN; ++t) {
            const float* __restrict__ row = dbc + (rbase + t) * 48;   // block-uniform
            float4 D0 = *(const float4*)(row);
            float4 D1 = *(const float4*)(row + 4);
            float4 D2 = *(const float4*)(row + 8);
            float4 D3 = *(const float4*)(row + 12);
            float4 B0 = *(const float4*)(row + 16);
            float4 B1 = *(const float4*)(row + 20);
            float4 B2 = *(const float4*)(row + 24);
            float4 B3 = *(const float4*)(row + 28);
            float4 C0 = *(const float4*)(row + 32);
            float4 C1 = *(const float4*)(row + 36);
            float4 C2 = *(const float4*)(row + 40);
            float4 C3 = *(const float4*)(row + 44);
            float Bv[16], Cv[16];
            *(float4*)&Bv[0] = B0; *(float4*)&Bv[4] = B1; *(float4*)&Bv[8] = B2; *(float4*)&Bv[12] = B3;
            *(float4*)&Cv[0] = C0; *(float4*)&Cv[4] = C1; *(float4*)&Cv[8] = C2; *(float4*)&Cv[12] = C3;
            float a0 = dbias + D0.x*wr[0] + D0.y*wr[1] + D0.z*wr[2] + D0.w*wr[3];
            float a1 = D1.x*wr[4] + D1.y*wr[5] + D1.z*wr[6] + D1.w*wr[7];
            float a2 = D2.x*wr[8] + D2.y*wr[9] + D2.z*wr[10] + D2.w*wr[11];
            float a3 = D3.x*wr[12] + D3.y*wr[13] + D3.z*wr[14] + D3.w*wr[15];
            float dot = (a0 + a1) + (a2 + a3);
            float dtv = (dot > 20.f) ? dot : __logf(1.f + __expf(dot));
            float xv  = __bfloat162float(xconv[(rbase + t) * DIN + d]);
            float wt  = __bfloat162float(zw   [(rbase + t) * DIN + d]);
            float u  = dtv * xv;
            dts += dtv;
            #pragma unroll
            for (int s = 0; s < 16; ++s) {
                float e = __expf(dtv * Aa[s]);
                ap[s] *= e;
                h[s] = e * h[s] + u * Bv[s];
                float tc = wt * Cv[s];
                acc += tc * h[s];
                g[s] += tc * ap[s];
            }
            acc += wt * xv * Dval;
        }
    }
    size_t o = (((size_t)b * NCH + c) * DIN + d) * 16;
    #pragma unroll
    for (int s = 0; s < 16; ++s) { hend[o + s] = h[s]; Gbuf[o + s] = g[s]; }
    sumdt [((size_t)b * NCH + c) * DIN + d] = dts;
    accloc[((size_t)b * NCH + c) * DIN + d] = acc;
}

// ---------------------------------------------------------------------------
// Phase 2a: per (b, group of 16 chunks, ds) combine chunks. ap recomputed
// as exp(A[s]*sumdt) (no aprod buffer). grid 2048 x 256.
// ---------------------------------------------------------------------------
__global__ __launch_bounds__(256)
void scan_p2a_kernel(const float* __restrict__ hend,
                     const float* __restrict__ sumdt,
                     const float* __restrict__ Gbuf,
                     const float* __restrict__ accloc,
                     const float* __restrict__ A_log,
                     float* __restrict__ hg, float* __restrict__ Pg,
                     float* __restrict__ Wg, float* __restrict__ part0g,
                     float* __restrict__ accg)
{
    const int g   = blockIdx.x * 256 + threadIdx.x;   // b*65536 + grp*8192 + ds
    const int b   = g >> 16;
    const int grp = (g >> 13) & 7;
    const int ds  = g & 8191;
    const int d   = ds >> 4;
    const int s   = ds & 15;
    const float Aa = -__expf(A_log[d * DSTATE + s]);
    float h = 0.f, P = 1.f, W = 0.f, p0 = 0.f;
    #pragma unroll
    for (int j = 0; j < NCH / NGRP; ++j) {
        int c = grp * (NCH / NGRP) + j;
        size_t idx = (((size_t)b * NCH + c) << 13) + ds;
        float G  = Gbuf[idx];
        float he = hend[idx];
        float ap = __expf(Aa * sumdt[((size_t)b * NCH + c) * DIN + d]);
        p0 += G * h;
        W  += G * P;
        h   = ap * h + he;
        P  *= ap;
    }
    size_t o = (((size_t)b * NGRP + grp) << 13) + ds;
    hg[o] = h; Pg[o] = P; Wg[o] = W; part0g[o] = p0;
    if (ds < DIN) {
        float a = 0.f;
        #pragma unroll
        for (int j = 0; j < NCH / NGRP; ++j)
            a += accloc[((size_t)b * NCH + grp * (NCH / NGRP) + j) * DIN + ds];
        accg[((size_t)b * NGRP + grp) * DIN + ds] = a;
    }
}

// ---------------------------------------------------------------------------
// Phase 2b: combine 8 groups, reduce over s, write ybar.
// ---------------------------------------------------------------------------
__global__ __launch_bounds__(256)
void scan_p2b_kernel(const float* __restrict__ hg, const float* __restrict__ Pg,
                     const float* __restrict__ Wg, const float* __restrict__ part0g,
                     const float* __restrict__ accg,
                     float* __restrict__ ybar)
{
    const int g  = blockIdx.x * 256 + threadIdx.x;
    const int b  = g >> 13;
    const int ds = g & 8191;
    const int d  = ds >> 4;
    const int s  = ds & 15;
    float h = 0.f, part = 0.f;
    #pragma unroll
    for (int grp = 0; grp < NGRP; ++grp) {
        size_t o = (((size_t)b * NGRP + grp) << 13) + ds;
        part += part0g[o] + Wg[o] * h;
        h = Pg[o] * h + hg[o];
    }
    part += __shfl_xor(part, 1, 64);
    part += __shfl_xor(part, 2, 64);
    part += __shfl_xor(part, 4, 64);
    part += __shfl_xor(part, 8, 64);
    if (s == 0) {
        float a = 0.f;
        #pragma unroll
        for (int grp = 0; grp < NGRP; ++grp)
            a += accg[((size_t)b * NGRP + grp) * DIN + d];
        ybar[b * DIN + d] = (part + a) * (1.f / (float)L_);
    }
}

// ---------------------------------------------------------------------------
// Head: one block per batch.
// ---------------------------------------------------------------------------
__global__ __launch_bounds__(256)
void head_kernel(const float* __restrict__ ybar,
                 const float* __restrict__ opw,
                 const float* __restrict__ clsw,
                 const float* __restrict__ clsb,
                 float* __restrict__ out)
{
    __shared__ float pooled_s[H_];
    __shared__ float logit_s[NCLS];
    const int tid = threadIdx.x;
    const int b   = blockIdx.x;
    const float* yb = ybar + b * DIN;
    const float* wr = opw + (size_t)tid * DIN;
    float p = 0.f;
    for (int dd = 0; dd < DIN; dd += 4) {
        float4 y4 = *(const float4*)(yb + dd);
        float4 w4 = *(const float4*)(wr + dd);
        p += y4.x*w4.x + y4.y*w4.y + y4.z*w4.z + y4.w*w4.w;
    }
    pooled_s[tid] = p;
    __syncthreads();
    if (tid < NCLS) {
        float lg = clsb[tid];
        const float* cw = clsw + tid * H_;
        for (int hh = 0; hh < H_; ++hh) lg += pooled_s[hh] * cw[hh];
        logit_s[tid] = lg;
        out[b * NCLS + tid] = lg;
    }
    __syncthreads();
    if (tid == 0) {
        float mx = logit_s[0];
        for (int c = 1; c < NCLS; ++c) mx = fmaxf(mx, logit_s[c]);
        float ssum = 0.f; float e[NCLS];
        for (int c = 0; c < NCLS; ++c) { e[c] = __expf(logit_s[c] - mx); ssum += e[c]; }
        for (int c = 0; c < NCLS; ++c) out[B_*NCLS + b * NCLS + c] = e[c] / ssum;
    }
}

// ---------------------------------------------------------------------------
extern "C" void kernel_launch(void* const* d_in, const int* in_sizes, int n_in,
                              void* d_out, int out_size, void* d_ws, size_t ws_size,
                              hipStream_t stream)
{
    const float* audio    = (const float*)d_in[0];
    const float* visual   = (const float*)d_in[1];
    const float* audio_w  = (const float*)d_in[2];
    const float* audio_b  = (const float*)d_in[3];
    const float* visual_w = (const float*)d_in[4];
    const float* visual_b = (const float*)d_in[5];
    const float* q_w = (const float*)d_in[6];
    const float* q_b = (const float*)d_in[7];
    const float* k_w = (const float*)d_in[8];
    const float* k_b = (const float*)d_in[9];
    const float* v_w = (const float*)d_in[10];
    const float* v_b = (const float*)d_in[11];
    const float* in_proj_w = (const float*)d_in[12];
    const float* conv_w    = (const float*)d_in[13];
    const float* conv_b    = (const float*)d_in[14];
    const float* x_proj_w  = (const float*)d_in[15];
    const float* dt_proj_w = (const float*)d_in[16];
    const float* dt_proj_b = (const float*)d_in[17];
    const float* A_log     = (const float*)d_in[18];
    const float* Dvec      = (const float*)d_in[19];
    const float* out_proj_w= (const float*)d_in[20];
    const float* cls_w     = (const float*)d_in[21];
    const float* cls_b     = (const float*)d_in[22];
    float* out = (float*)d_out;
    float* ws  = (float*)d_ws;

    // ---- workspace (float offsets), peak unchanged (< 33.55M floats) ----
    __hip_bfloat16* abf  = (__hip_bfloat16*)(ws);               // [0, 4.19M)
    __hip_bfloat16* vbf  = (__hip_bfloat16*)(ws + 4194304);     // [4.19M, 8.39M)
    __hip_bfloat16* Qbf  = (__hip_bfloat16*)(ws + 8388608);
    __hip_bfloat16* KVbf = (__hip_bfloat16*)(ws + 10485760);
    __hip_bfloat16* Vt   = (__hip_bfloat16*)(ws + 14680064);
    __hip_bfloat16* fusedbf = (__hip_bfloat16*)(ws + 16777216); // [16.78M, 18.87M)
    __hip_bfloat16* Opart   = (__hip_bfloat16*)(ws + 18874368); // [18.87M, 27.26M)
    __hip_bfloat16* xconvbf = (__hip_bfloat16*)(ws + 27262976); // [27.26M, 31.46M)
    // post-merge reuse:
    __hip_bfloat16* xbufbf = (__hip_bfloat16*)(ws);             // abf region (dead)
    __hip_bfloat16* zwbf   = (__hip_bfloat16*)(ws + 4194304);   // vbf region (dead)
    // scan buffers (NCH=128 layout):
    float* sumdt  = ws;             // [0, 0.52M)        abf region (dead after conv)
    float* accloc = ws + 524288;    // [0.52M, 1.05M)    abf region
    float* hend   = ws + 8388608;   // [8.39M, 16.78M)   Qbf+KVbf+Vt (dead after attn)
    float* Gbuf   = ws + 18874368;  // [18.87M, 27.26M)  Opart (dead after merge)
    float* hg     = ws + 16777216;  // fusedbf region (dead after X/Z)
    float* Pg     = ws + 17301504;
    float* Wgb    = ws + 17825792;
    float* part0g = ws + 18350080;  // ends 18874368
    // small regions:
    __hip_bfloat16* q_wbf   = (__hip_bfloat16*)(ws + 31457280);
    __hip_bfloat16* k_wbf   = (__hip_bfloat16*)(ws + 31490048);
    __hip_bfloat16* v_wbf   = (__hip_bfloat16*)(ws + 31522816);
    __hip_bfloat16* ipwbf   = (__hip_bfloat16*)(ws + 31555584);
    __hip_bfloat16* xpwbf   = (__hip_bfloat16*)(ws + 31686656);
    __hip_bfloat16* awT     = (__hip_bfloat16*)(ws + 31698944);
    __hip_bfloat16* vwT     = (__hip_bfloat16*)(ws + 31764480);
    __hip_bfloat16* Wqp     = (__hip_bfloat16*)(ws + 31830016);
    __hip_bfloat16* Wkvp    = (__hip_bfloat16*)(ws + 31895552);
    float* bq     = ws + 32026624;
    float* bkv    = ws + 32026880;
    float* lpart  = ws + 32027392;   // 65536
    float* dbcb   = ws + 32092928;   // 786432 -> ends 32879360
    float* accg   = ws + 33141504;   // 32768  -> ends 33174272
    float* ybar   = ws + 33174272;   // 4096   -> ends 33178368
    (void)ws_size;

    dim3 blk(256);
    // ---- prep (2 launches, R11: cast+prep fused)
    cast_prep_kernel<<<dim3(9455), blk, 0, stream>>>(audio, visual, abf, vbf,
                                                     q_w, k_w, v_w, in_proj_w, x_proj_w,
                                                     audio_w, visual_w, audio_b, visual_b,
                                                     q_b, k_b, v_b,
                                                     q_wbf, k_wbf, v_wbf, ipwbf, xpwbf,
                                                     awT, vwT, bq, bkv);
    gemm_comp_kernel<<<dim3(16, 8, 3), dim3(64), 0, stream>>>(q_wbf, k_wbf, v_wbf, awT, vwT, Wqp, Wkvp);
    // ---- fused projections (R11: Q+KV in one launch)
    gemm8_qkv_kernel<<<dim3(128, 12), blk, 0, stream>>>(abf, vbf, Wqp, Wkvp, bq, bkv, Qbf, KVbf);
    // ---- attention
    transpose_v_kernel<<<dim3(2048), blk, 0, stream>>>(KVbf, Vt);
    attn_split_kernel<<<dim3(512), blk, 0, stream>>>(Qbf, KVbf, Vt, Opart, lpart);
    attn_merge_kernel<<<dim3(2048), blk, 0, stream>>>(Opart, lpart, fusedbf);
    // ---- mamba in_proj (R11: x+z in one launch)
    gemm8_xz_kernel<<<dim3(128, 16), blk, 0, stream>>>(fusedbf, ipwbf, xbufbf, zwbf);
    conv_silu_kernel<<<dim3(4096), blk, 0, stream>>>(xbufbf, conv_w, conv_b, xconvbf);
    // ---- x_proj (N=48)
    gemm4_t<48, 512, 3, 0, 0><<<dim3(256, 1), blk, 0, stream>>>(xconvbf, xpwbf, nullptr, dbcb);
    // ---- merged chunked scan + two-level combine (p1: NCH=128, grid 2048)
    scan_p1_kernel<<<dim3(2048), blk, 0, stream>>>(xconvbf, zwbf, dbcb, dt_proj_w, dt_proj_b,
                                                   A_log, Dvec, hend, sumdt, Gbuf, accloc);
    scan_p2a_kernel<<<dim3(2048), blk, 0, stream>>>(hend, sumdt, Gbuf, accloc, A_log,
                                                    hg, Pg, Wgb, part0g, accg);
    scan_p2b_kernel<<<dim3(256), blk, 0, stream>>>(hg, Pg, Wgb, part0g, accg, ybar);
    // ---- head
    head_kernel<<<dim3(8), blk, 0, stream>>>(ybar, out_proj_w, cls_w, cls_b, out);
}

// Round 12
// 405.293 us; speedup vs baseline: 1.0305x; 1.0305x over previous
//
#include <hip/hip_runtime.h>
#include <hip/hip_bf16.h>
#include <math.h>

#define B_    8
#define L_    2048
#define AD    512
#define VD    512
#define H_    256
#define DIN   512
#define DSTATE 16
#define DCONV  4
#define DTRANK 16
#define NCLS   8
#define BL    (B_ * L_)   // 16384
#define NCH   128
#define CLEN  16
#define NSP   4
#define NGRP  8           // scan p2 groups (NCH/NGRP = 16 chunks each)

typedef __attribute__((ext_vector_type(8))) short bf16x8;
typedef __attribute__((ext_vector_type(4))) float f32x4;

__device__ inline bf16x8 pack8(float4 a, float4 b)
{
    bf16x8 o; __hip_bfloat16 t;
    t = __float2bfloat16(a.x); o[0] = *(short*)&t;
    t = __float2bfloat16(a.y); o[1] = *(short*)&t;
    t = __float2bfloat16(a.z); o[2] = *(short*)&t;
    t = __float2bfloat16(a.w); o[3] = *(short*)&t;
    t = __float2bfloat16(b.x); o[4] = *(short*)&t;
    t = __float2bfloat16(b.y); o[5] = *(short*)&t;
    t = __float2bfloat16(b.z); o[6] = *(short*)&t;
    t = __float2bfloat16(b.w); o[7] = *(short*)&t;
    return o;
}

// Direct global->LDS DMA, 16B per lane. LDS dest must be wave-uniform base;
// HW writes base + lane*16. Global src is per-lane (enables swizzled layouts).
__device__ __forceinline__ void gload_lds16(const void* g, void* l)
{
    __builtin_amdgcn_global_load_lds(
        (const __attribute__((address_space(1))) void*)g,
        (__attribute__((address_space(3))) void*)l,
        16, 0, 0);
}

// ---------------------------------------------------------------------------
// R11: fused cast_inputs + prep (independent work, one launch).
// blocks [0,8192): input casts. [8192,8428): weight casts.
// [8428,9452): wT transposes. [9452,9455): bias fold.
// ---------------------------------------------------------------------------
__global__ __launch_bounds__(256)
void cast_prep_kernel(const float* __restrict__ a, const float* __restrict__ v,
                      __hip_bfloat16* __restrict__ ab, __hip_bfloat16* __restrict__ vbf_,
                      const float* __restrict__ qw, const float* __restrict__ kw,
                      const float* __restrict__ vw, const float* __restrict__ ipw,
                      const float* __restrict__ xpw,
                      const float* __restrict__ aw, const float* __restrict__ vww,
                      const float* __restrict__ ab2, const float* __restrict__ vb,
                      const float* __restrict__ qb, const float* __restrict__ kb,
                      const float* __restrict__ vb2,
                      __hip_bfloat16* __restrict__ qwb, __hip_bfloat16* __restrict__ kwb,
                      __hip_bfloat16* __restrict__ vwb, __hip_bfloat16* __restrict__ ipwb,
                      __hip_bfloat16* __restrict__ xpwb,
                      __hip_bfloat16* __restrict__ awT, __hip_bfloat16* __restrict__ vwT,
                      float* __restrict__ bq, float* __restrict__ bkv)
{
    const int bx = blockIdx.x;
    if (bx < 8192) {
        size_t i = ((size_t)bx * 256 + threadIdx.x) * 8;
        const float* s; __hip_bfloat16* d; size_t off;
        if (i < 8388608) { s = a; d = ab; off = i; }
        else             { s = v; d = vbf_; off = i - 8388608; }
        float4 x = *(const float4*)(s + off);
        float4 y = *(const float4*)(s + off + 4);
        *(bf16x8*)(d + off) = pack8(x, y);
        return;
    }
    const int blk = bx - 8192;
    if (blk < 236) {
        size_t i = ((size_t)blk * 256 + threadIdx.x) * 8;
        const float* s; __hip_bfloat16* d; size_t off;
        if      (i <  65536) { s = qw;  d = qwb;  off = i; }
        else if (i < 131072) { s = kw;  d = kwb;  off = i - 65536; }
        else if (i < 196608) { s = vw;  d = vwb;  off = i - 131072; }
        else if (i < 458752) { s = ipw; d = ipwb; off = i - 196608; }
        else                 { s = xpw; d = xpwb; off = i - 458752; }
        float4 x = *(const float4*)(s + off);
        float4 y = *(const float4*)(s + off + 4);
        *(bf16x8*)(d + off) = pack8(x, y);
    } else if (blk < 1260) {
        int i = (blk - 236) * 256 + threadIdx.x;       // 0..262143
        const float* s = (i < 131072) ? aw : vww;
        __hip_bfloat16* d = (i < 131072) ? awT : vwT;
        int j = i & 131071;
        int r = j >> 9, c = j & 511;
        d[c * 256 + r] = __float2bfloat16(s[j]);
    } else {
        int seg = blk - 1260;
        int m = threadIdx.x;
        const float* w  = (seg == 0) ? qw : (seg == 1) ? kw : vw;
        const float* ib = (seg == 0) ? ab2 : vb;
        const float* ob = (seg == 0) ? qb : (seg == 1) ? kb : vb2;
        float s = ob[m];
        for (int i = 0; i < 256; ++i) s += w[m * 256 + i] * ib[i];
        if (seg == 0) bq[m] = s;
        else          bkv[(seg - 1) * 256 + m] = s;
    }
}

// ---------------------------------------------------------------------------
// Fused weight-composition GEMMs: z=0: Wq'=q_w@awT; z=1/2: Wk'/Wv'=@vwT.
// 16-row/wave, N=512, K=256, bf16 out. grid (16, 8, 3).
// ---------------------------------------------------------------------------
__global__ __launch_bounds__(64, 2)
void gemm_comp_kernel(const __hip_bfloat16* __restrict__ qw,
                      const __hip_bfloat16* __restrict__ kw,
                      const __hip_bfloat16* __restrict__ vw,
                      const __hip_bfloat16* __restrict__ awT,
                      const __hip_bfloat16* __restrict__ vwT,
                      __hip_bfloat16* __restrict__ Wqp,
                      __hip_bfloat16* __restrict__ Wkvp)
{
    const int seg = blockIdx.z;
    const __hip_bfloat16* A = (seg == 0) ? qw : (seg == 1) ? kw : vw;
    const __hip_bfloat16* W = (seg == 0) ? awT : vwT;
    __hip_bfloat16* outp = (seg == 0) ? Wqp : (Wkvp + (size_t)(seg - 1) * 256 * 512);

    const int lane = threadIdx.x;
    const int l15  = lane & 15;
    const int quad = lane >> 4;
    const int m0   = blockIdx.x * 16;
    const int n0   = blockIdx.y * 64;

    const __hip_bfloat16* Arow = A + (size_t)(m0 + l15) * 256 + quad * 8;
    f32x4 acc[4];
    #pragma unroll
    for (int nt = 0; nt < 4; ++nt) acc[nt] = (f32x4){0.f, 0.f, 0.f, 0.f};

    #pragma unroll
    for (int kc = 0; kc < 256; kc += 32) {
        bf16x8 af = *(const bf16x8*)(Arow + kc);
        #pragma unroll
        for (int nt = 0; nt < 4; ++nt) {
            bf16x8 bfv = *(const bf16x8*)(W + (size_t)(n0 + nt * 16 + l15) * 256 + kc + quad * 8);
            acc[nt] = __builtin_amdgcn_mfma_f32_16x16x32_bf16(af, bfv, acc[nt], 0, 0, 0);
        }
    }
    #pragma unroll
    for (int nt = 0; nt < 4; ++nt) {
        int col = n0 + nt * 16 + l15;
        #pragma unroll
        for (int r = 0; r < 4; ++r)
            outp[(size_t)(m0 + quad * 4 + r) * 512 + col] = __float2bfloat16(acc[nt][r]);
    }
}

// ---------------------------------------------------------------------------
// gemm4_t: 4-wave blocks, 64 rows x NT*16 cols. W staged in LDS (264-pad).
// (kept for xproj N=48)
// ---------------------------------------------------------------------------
template<int N, int K, int NT, int OBF, int ACT>
__global__ __launch_bounds__(256, 2)
void gemm4_t(const __hip_bfloat16* __restrict__ A,
             const __hip_bfloat16* __restrict__ W,
             const float* __restrict__ bias,
             void* __restrict__ outp)
{
    constexpr int NROWS = NT * 16;
    __shared__ __attribute__((aligned(16))) short Ws[NROWS * 264];
    const int tid  = threadIdx.x;
    const int lane = tid & 63;
    const int w    = tid >> 6;
    const int l15  = lane & 15;
    const int quad = lane >> 4;
    const int m0   = blockIdx.x * 64 + w * 16;
    const int n0   = blockIdx.y * 64;

    constexpr int KC = K / 32;
    bf16x8 af[KC];
    const __hip_bfloat16* Arow = A + (size_t)(m0 + l15) * K + quad * 8;
    #pragma unroll
    for (int kc = 0; kc < KC; ++kc) af[kc] = *(const bf16x8*)(Arow + kc * 32);

    f32x4 acc[NT];
    #pragma unroll
    for (int nt = 0; nt < NT; ++nt) acc[nt] = (f32x4){0.f, 0.f, 0.f, 0.f};

    #pragma unroll
    for (int kh = 0; kh < K / 256; ++kh) {
        __syncthreads();
        #pragma unroll
        for (int i = 0; i < 8; ++i) {
            int id = tid + i * 256;
            int row = id >> 5, c = id & 31;
            if (row < NROWS)
                *(bf16x8*)&Ws[row * 264 + c * 8] =
                    *(const bf16x8*)(W + (size_t)(n0 + row) * K + kh * 256 + c * 8);
        }
        __syncthreads();
        #pragma unroll
        for (int kc = 0; kc < 8; ++kc) {
            #pragma unroll
            for (int nt = 0; nt < NT; ++nt) {
                bf16x8 wv = *(const bf16x8*)&Ws[(nt * 16 + l15) * 264 + kc * 32 + quad * 8];
                acc[nt] = __builtin_amdgcn_mfma_f32_16x16x32_bf16(af[kh * 8 + kc], wv, acc[nt], 0, 0, 0);
            }
        }
    }
    #pragma unroll
    for (int nt = 0; nt < NT; ++nt) {
        int col = n0 + nt * 16 + l15;
        float bv = bias ? bias[col] : 0.f;
        #pragma unroll
        for (int r = 0; r < 4; ++r) {
            size_t idx = (size_t)(m0 + quad * 4 + r) * N + col;
            float v = acc[nt][r] + bv;
            if (ACT) v = v / (1.f + __expf(-v));
            if (OBF) ((__hip_bfloat16*)outp)[idx] = __float2bfloat16(v);
            else     ((float*)outp)[idx] = v;
        }
    }
}

// ---------------------------------------------------------------------------
// gemm8 body (R10 structure): 4-wave blocks, 128 rows x 64 cols per block,
// each wave owns TWO 16-row sets -> every LDS B-frag feeds 2 MFMAs.
// Runtime N/n0/act (block-uniform). acc order identical to gemm4_t.
// ---------------------------------------------------------------------------
template<int K>
__device__ __forceinline__ void gemm8_body(
    const __hip_bfloat16* __restrict__ A,
    const __hip_bfloat16* __restrict__ W,
    const float* __restrict__ bias,
    __hip_bfloat16* __restrict__ outp,
    int N, int n0, int act, short* Ws)
{
    constexpr int NT = 4;
    const int tid  = threadIdx.x;
    const int lane = tid & 63;
    const int w    = tid >> 6;
    const int l15  = lane & 15;
    const int quad = lane >> 4;
    const int m0   = blockIdx.x * 128 + w * 32;

    f32x4 acc[2][NT];
    #pragma unroll
    for (int s2 = 0; s2 < 2; ++s2)
        #pragma unroll
        for (int nt = 0; nt < NT; ++nt) acc[s2][nt] = (f32x4){0.f, 0.f, 0.f, 0.f};

    #pragma unroll
    for (int kh = 0; kh < K / 256; ++kh) {
        bf16x8 af[2][8];
        #pragma unroll
        for (int s2 = 0; s2 < 2; ++s2)
            #pragma unroll
            for (int kc = 0; kc < 8; ++kc)
                af[s2][kc] = *(const bf16x8*)(A + (size_t)(m0 + s2 * 16 + l15) * K
                                              + kh * 256 + kc * 32 + quad * 8);
        __syncthreads();
        #pragma unroll
        for (int i = 0; i < 8; ++i) {
            int id = tid + i * 256;
            int row = id >> 5, c = id & 31;
            *(bf16x8*)&Ws[row * 264 + c * 8] =
                *(const bf16x8*)(W + (size_t)(n0 + row) * K + kh * 256 + c * 8);
        }
        __syncthreads();
        #pragma unroll
        for (int kc = 0; kc < 8; ++kc) {
            #pragma unroll
            for (int nt = 0; nt < NT; ++nt) {
                bf16x8 wv = *(const bf16x8*)&Ws[(nt * 16 + l15) * 264 + kc * 32 + quad * 8];
                acc[0][nt] = __builtin_amdgcn_mfma_f32_16x16x32_bf16(af[0][kc], wv, acc[0][nt], 0, 0, 0);
                acc[1][nt] = __builtin_amdgcn_mfma_f32_16x16x32_bf16(af[1][kc], wv, acc[1][nt], 0, 0, 0);
            }
        }
    }
    #pragma unroll
    for (int s2 = 0; s2 < 2; ++s2)
        #pragma unroll
        for (int nt = 0; nt < NT; ++nt) {
            int col = n0 + nt * 16 + l15;
            float bv = bias ? bias[col] : 0.f;
            #pragma unroll
            for (int r = 0; r < 4; ++r) {
                size_t idx = (size_t)(m0 + s2 * 16 + quad * 4 + r) * N + col;
                float v = acc[s2][nt][r] + bv;
                if (act) v = v / (1.f + __expf(-v));
                outp[idx] = __float2bfloat16(v);
            }
        }
}

// R11: Q + KV projections in ONE launch. grid (128, 12): y<4 -> Q (N=256),
// else KV (N=512). K=512.
__global__ __launch_bounds__(256)
void gemm8_qkv_kernel(const __hip_bfloat16* __restrict__ abf,
                      const __hip_bfloat16* __restrict__ vbf,
                      const __hip_bfloat16* __restrict__ Wqp,
                      const __hip_bfloat16* __restrict__ Wkvp,
                      const float* __restrict__ bq,
                      const float* __restrict__ bkv,
                      __hip_bfloat16* __restrict__ Qbf,
                      __hip_bfloat16* __restrict__ KVbf)
{
    __shared__ __attribute__((aligned(16))) short Ws[64 * 264];
    const int y = blockIdx.y;
    if (y < 4)
        gemm8_body<512>(abf, Wqp,  bq,  Qbf,  256, y * 64,       0, Ws);
    else
        gemm8_body<512>(vbf, Wkvp, bkv, KVbf, 512, (y - 4) * 64, 0, Ws);
}

// R11: in_proj x + z in ONE launch. grid (128, 16): y<8 -> x (ACT=0),
// else z (ACT=1, silu). N=512, K=256.
__global__ __launch_bounds__(256)
void gemm8_xz_kernel(const __hip_bfloat16* __restrict__ fusedbf,
                     const __hip_bfloat16* __restrict__ ipwbf,
                     __hip_bfloat16* __restrict__ xbufbf,
                     __hip_bfloat16* __restrict__ zwbf)
{
    __shared__ __attribute__((aligned(16))) short Ws[64 * 264];
    const int y = blockIdx.y;
    if (y < 8)
        gemm8_body<256>(fusedbf, ipwbf,             nullptr, xbufbf, 512, y * 64,       0, Ws);
    else
        gemm8_body<256>(fusedbf, ipwbf + DIN * H_,  nullptr, zwbf,   512, (y - 8) * 64, 1, Ws);
}

// ---------------------------------------------------------------------------
// V transpose from stacked KV -> Vt[b][h][l]
// ---------------------------------------------------------------------------
__global__ __launch_bounds__(256)
void transpose_v_kernel(const __hip_bfloat16* __restrict__ KV,
                        __hip_bfloat16* __restrict__ Vt)
{
    const int tid = threadIdx.x;
    const int lc  = blockIdx.x & 7;
    const int hg  = (blockIdx.x >> 3) & 31;
    const int b   = blockIdx.x >> 8;
    const int l   = lc * 256 + tid;
    bf16x8 v = *(const bf16x8*)(KV + ((size_t)b * L_ + l) * 512 + 256 + hg * 8);
    __hip_bfloat16* dst = Vt + (size_t)b * H_ * L_ + (size_t)(hg * 8) * L_ + l;
    #pragma unroll
    for (int j = 0; j < 8; ++j) {
        short s = v[j];
        dst[(size_t)j * L_] = *(__hip_bfloat16*)&s;
    }
}

// ---------------------------------------------------------------------------
// Attention: 4 waves/block, 32 queries/WAVE, 128 q/block, 512 keys per split.
// R3: double-buffered LDS K/V staged via global_load_lds DMA (zero VGPR cost,
//     T3 2-phase). XOR chunk swizzle on global source + ds_read side.
// ---------------------------------------------------------------------------
__global__ __launch_bounds__(256, 2)
void attn_split_kernel(const __hip_bfloat16* __restrict__ Q,
                       const __hip_bfloat16* __restrict__ KV,
                       const __hip_bfloat16* __restrict__ Vt,
                       __hip_bfloat16* __restrict__ Opart,
                       float* __restrict__ lpart)
{
    __shared__ __attribute__((aligned(16))) short Ks[2][32 * 256];   // [key][256 sh], swz
    __shared__ __attribute__((aligned(16))) short Vs[2][256 * 32];   // [h][32 sh], swz
    __shared__ __attribute__((aligned(16))) short Pls[4][2][16 * 40];

    const int tid  = threadIdx.x;
    const int lane = tid & 63;
    const int w    = tid >> 6;
    const int b    = blockIdx.x & 7;
    const int qt   = (blockIdx.x >> 3) & 15;
    const int sp   = blockIdx.x >> 7;
    const int q0   = qt * 128 + w * 32;
    const int l15  = lane & 15;
    const int quad = lane >> 4;
    const int wb   = tid & 192;        // wave-uniform chunk base (w*64)

    const __hip_bfloat16* Qb = Q  + ((size_t)b * L_ + q0) * H_;
    const __hip_bfloat16* Kb = KV + (size_t)b * L_ * 512;
    const __hip_bfloat16* Vb = Vt + (size_t)b * H_ * L_;

    bf16x8 qf[2][8];
    #pragma unroll
    for (int s2 = 0; s2 < 2; ++s2)
        #pragma unroll
        for (int kc = 0; kc < 8; ++kc)
            qf[s2][kc] = *(const bf16x8*)(Qb + (size_t)(s2 * 16 + l15) * H_ + kc * 32 + quad * 8);

    f32x4 Oacc[2][16];
    #pragma unroll
    for (int s2 = 0; s2 < 2; ++s2)
        #pragma unroll
        for (int nt = 0; nt < 16; ++nt) Oacc[s2][nt] = (f32x4){0.f, 0.f, 0.f, 0.f};
    float lsum[2][4] = {{0.f,0.f,0.f,0.f},{0.f,0.f,0.f,0.f}};

    const int kbase = sp * 512;
    const int sK = l15 & 7;                       // K read swizzle (row&7)
    const int vcol8 = (quad ^ (l15 & 3)) * 8;     // V read swizzle (row&3)

    // DMA staging: 1024 chunks of 16B each for K and V per tile.
#define STAGE(KsD, VsD, stv) do {                                                 \
        const int kb_ = kbase + (stv) * 32;                                       \
        _Pragma("unroll")                                                         \
        for (int i_ = 0; i_ < 4; ++i_) {                                          \
            int q_ = i_ * 256 + tid;                                              \
            int rK_ = q_ >> 5, cK_ = q_ & 31;                                     \
            gload_lds16(Kb + (size_t)(kb_ + rK_) * 512 + ((cK_ ^ (rK_ & 7)) << 3),\
                        (KsD) + (i_ * 256 + wb) * 8);                             \
            int rV_ = q_ >> 2, cV_ = q_ & 3;                                      \
            gload_lds16(Vb + (size_t)rV_ * L_ + kb_ + ((cV_ ^ (rV_ & 3)) << 3),   \
                        (VsD) + (i_ * 256 + wb) * 8);                             \
        }                                                                         \
    } while (0)

    STAGE(Ks[0], Vs[0], 0);
    __syncthreads();                               // vmcnt(0): tile 0 landed
    for (int st = 0; st < 16; ++st) {
        const int cur = st & 1;
        short* KsC = Ks[cur];
        short* VsC = Vs[cur];
        if (st < 15) STAGE(Ks[cur ^ 1], Vs[cur ^ 1], st + 1);  // async, drains at bottom barrier
        // ---- S = Q K^T : each K-frag feeds both q-sets
        #pragma unroll
        for (int nt = 0; nt < 2; ++nt) {
            f32x4 S0 = (f32x4){0.f,0.f,0.f,0.f};
            f32x4 S1 = (f32x4){0.f,0.f,0.f,0.f};
            __builtin_amdgcn_s_setprio(1);
            #pragma unroll
            for (int kc = 0; kc < 8; ++kc) {
                bf16x8 bk = *(const bf16x8*)&KsC[(nt * 16 + l15) * 256 + (((kc * 4 + quad) ^ sK) << 3)];
                S0 = __builtin_amdgcn_mfma_f32_16x16x32_bf16(qf[0][kc], bk, S0, 0, 0, 0);
                S1 = __builtin_amdgcn_mfma_f32_16x16x32_bf16(qf[1][kc], bk, S1, 0, 0, 0);
            }
            __builtin_amdgcn_s_setprio(0);
            #pragma unroll
            for (int r = 0; r < 4; ++r) {
                float p0 = __expf(S0[r] * 0.0625f);
                float p1 = __expf(S1[r] * 0.0625f);
                lsum[0][r] += p0;
                lsum[1][r] += p1;
                __hip_bfloat16 pb0 = __float2bfloat16(p0);
                __hip_bfloat16 pb1 = __float2bfloat16(p1);
                Pls[w][0][(quad * 4 + r) * 40 + nt * 16 + l15] = *(short*)&pb0;
                Pls[w][1][(quad * 4 + r) * 40 + nt * 16 + l15] = *(short*)&pb1;
            }
        }
        bf16x8 pf0 = *(const bf16x8*)&Pls[w][0][l15 * 40 + quad * 8];
        bf16x8 pf1 = *(const bf16x8*)&Pls[w][1][l15 * 40 + quad * 8];
        // ---- O += P V : each V-frag feeds both q-sets
        __builtin_amdgcn_s_setprio(1);
        #pragma unroll
        for (int nt = 0; nt < 16; ++nt) {
            bf16x8 vf = *(const bf16x8*)&VsC[(nt * 16 + l15) * 32 + vcol8];
            Oacc[0][nt] = __builtin_amdgcn_mfma_f32_16x16x32_bf16(pf0, vf, Oacc[0][nt], 0, 0, 0);
            Oacc[1][nt] = __builtin_amdgcn_mfma_f32_16x16x32_bf16(pf1, vf, Oacc[1][nt], 0, 0, 0);
        }
        __builtin_amdgcn_s_setprio(0);
        __syncthreads();    // compute(cur) done + next tile's DMA drained (vmcnt 0)
    }
#undef STAGE
    #pragma unroll
    for (int s2 = 0; s2 < 2; ++s2)
        #pragma unroll
        for (int r = 0; r < 4; ++r) {
            lsum[s2][r] += __shfl_xor(lsum[s2][r], 1, 64);
            lsum[s2][r] += __shfl_xor(lsum[s2][r], 2, 64);
            lsum[s2][r] += __shfl_xor(lsum[s2][r], 4, 64);
            lsum[s2][r] += __shfl_xor(lsum[s2][r], 8, 64);
        }
    __hip_bfloat16* Ob = Opart + (((size_t)sp * B_ + b) * L_ + q0) * H_;
    #pragma unroll
    for (int s2 = 0; s2 < 2; ++s2)
        #pragma unroll
        for (int r = 0; r < 4; ++r)
            #pragma unroll
            for (int nt = 0; nt < 16; ++nt)
                Ob[(size_t)(s2 * 16 + quad * 4 + r) * H_ + nt * 16 + l15] =
                    __float2bfloat16(Oacc[s2][nt][r]);
    if (l15 == 0) {
        #pragma unroll
        for (int s2 = 0; s2 < 2; ++s2)
            #pragma unroll
            for (int r = 0; r < 4; ++r)
                lpart[((size_t)sp * B_ + b) * L_ + q0 + s2 * 16 + quad * 4 + r] = lsum[s2][r];
    }
}

// ---------------------------------------------------------------------------
// Merge attention splits. R7: bf16x8-vectorized. grid 2048.
// ---------------------------------------------------------------------------
__global__ __launch_bounds__(256)
void attn_merge_kernel(const __hip_bfloat16* __restrict__ Opart,
                       const float* __restrict__ lpart,
                       __hip_bfloat16* __restrict__ O)
{
    const size_t i8  = ((size_t)blockIdx.x * 256 + threadIdx.x) * 8;
    const size_t row = i8 >> 8;
    float l = 0.f;
    #pragma unroll
    for (int sp = 0; sp < NSP; ++sp) l += lpart[(size_t)sp * BL + row];
    const float inv = 1.f / l;
    float o[8] = {0.f,0.f,0.f,0.f,0.f,0.f,0.f,0.f};
    #pragma unroll
    for (int sp = 0; sp < NSP; ++sp) {
        bf16x8 v = *(const bf16x8*)(Opart + (size_t)sp * BL * H_ + i8);
        #pragma unroll
        for (int j = 0; j < 8; ++j) {
            short s = v[j];
            o[j] += __bfloat162float(*(__hip_bfloat16*)&s);
        }
    }
    bf16x8 ov;
    #pragma unroll
    for (int j = 0; j < 8; ++j) {
        __hip_bfloat16 t = __float2bfloat16(o[j] * inv);
        ov[j] = *(short*)&t;
    }
    *(bf16x8*)(O + i8) = ov;
}

// ---------------------------------------------------------------------------
// Depthwise causal conv (k=4) + bias + silu: bf16 in, bf16 out.
// R7: 8 channels/thread, bf16x8 tap loads + bf16x8 store. grid 4096.
// ---------------------------------------------------------------------------
__global__ __launch_bounds__(256)
void conv_silu_kernel(const __hip_bfloat16* __restrict__ xb,
                      const float* __restrict__ cw,
                      const float* __restrict__ cb,
                      __hip_bfloat16* __restrict__ xconvbf)
{
    const int idx = blockIdx.x * 256 + threadIdx.x;   // [0, BL*DIN/8)
    const int d0 = (idx & 63) << 3;
    const int l  = (idx >> 6) & (L_ - 1);
    const int b  = idx >> 17;

    float4 wv[8];
    float acc[8];
    #pragma unroll
    for (int j = 0; j < 8; ++j) {
        wv[j]  = *(const float4*)(cw + (d0 + j) * DCONV);
        acc[j] = cb[d0 + j];
    }
    #pragma unroll
    for (int t = 0; t < DCONV; ++t) {
        int ls = l - (DCONV - 1) + t;
        if (ls >= 0) {
            bf16x8 x = *(const bf16x8*)(xb + ((size_t)b * L_ + ls) * DIN + d0);
            #pragma unroll
            for (int j = 0; j < 8; ++j) {
                short s = x[j];
                float xv = __bfloat162float(*(__hip_bfloat16*)&s);
                float wt = (t == 0) ? wv[j].x : (t == 1) ? wv[j].y : (t == 2) ? wv[j].z : wv[j].w;
                acc[j] += xv * wt;
            }
        }
    }
    bf16x8 ov;
    #pragma unroll
    for (int j = 0; j < 8; ++j) {
        float v = acc[j] / (1.f + __expf(-acc[j]));
        __hip_bfloat16 t = __float2bfloat16(v);
        ov[j] = *(short*)&t;
    }
    *(bf16x8*)(xconvbf + (size_t)idx * 8) = ov;
}

// ---------------------------------------------------------------------------
// Merged scan phase 1. R12: s-major state layout -- hend/Gbuf stored at
// chunkbase + s*DIN + d so each of the 32 epilogue stores is a COALESCED
// 1KB wave-store (was d-major: adjacent lanes 64B apart -> ~64 transactions
// per store instruction, ~65K trans/CU hidden in the kernel tail; this is
// the arithmetic explanation for the 55us plateau). Pure layout permutation,
// bitwise-identical math. dbc via uniform s_loads (R9), NCH=128/CLEN=16 +
// sumdt (R8) retained.
// ---------------------------------------------------------------------------
__global__ __launch_bounds__(256)
void scan_p1_kernel(const __hip_bfloat16* __restrict__ xconv,
                    const __hip_bfloat16* __restrict__ zw,
                    const float* __restrict__ dbc,
                    const float* __restrict__ dtw,
                    const float* __restrict__ dtbias,
                    const float* __restrict__ A_log,
                    const float* __restrict__ Dv,
                    float* __restrict__ hend,
                    float* __restrict__ sumdt,
                    float* __restrict__ Gbuf,
                    float* __restrict__ accloc)
{
    const int tid  = threadIdx.x;
    const int dgrp = blockIdx.x & 1;
    const int c    = (blockIdx.x >> 1) & (NCH - 1);
    const int b    = blockIdx.x >> 8;
    const int d    = dgrp * 256 + tid;
    const size_t rbase = (size_t)b * L_ + c * CLEN;

    float wr[16];
    #pragma unroll
    for (int r = 0; r < 16; ++r) wr[r] = dtw[d * DTRANK + r];
    const float dbias = dtbias[d];
    const float Dval  = Dv[d];

    float Aa[16];
    bool fast = true;
    #pragma unroll
    for (int s = 0; s < 16; ++s) {
        Aa[s] = -__expf(A_log[d * DSTATE + s]);
        fast = fast && (fabsf(Aa[s] + (float)(s + 1)) < 1e-3f);
    }

    float h[16], ap[16], g[16];
    #pragma unroll
    for (int s = 0; s < 16; ++s) { h[s] = 0.f; ap[s] = 1.f; g[s] = 0.f; }
    float acc = 0.f;
    float dts = 0.f;

    if (fast) {
        for (int t = 0; t < CLEN; ++t) {
            const float* __restrict__ row = dbc + (rbase + t) * 48;   // block-uniform
            float4 D0 = *(const float4*)(row);
            float4 D1 = *(const float4*)(row + 4);
            float4 D2 = *(const float4*)(row + 8);
            float4 D3 = *(const float4*)(row + 12);
            float4 B0 = *(const float4*)(row + 16);
            float4 B1 = *(const float4*)(row + 20);
            float4 B2 = *(const float4*)(row + 24);
            float4 B3 = *(const float4*)(row + 28);
            float4 C0 = *(const float4*)(row + 32);
            float4 C1 = *(const float4*)(row + 36);
            float4 C2 = *(const float4*)(row + 40);
            float4 C3 = *(const float4*)(row + 44);
            float Bv[16], Cv[16];
            *(float4*)&Bv[0] = B0; *(float4*)&Bv[4] = B1; *(float4*)&Bv[8] = B2; *(float4*)&Bv[12] = B3;
            *(float4*)&Cv[0] = C0; *(float4*)&Cv[4] = C1; *(float4*)&Cv[8] = C2; *(float4*)&Cv[12] = C3;
            float a0 = dbias + D0.x*wr[0] + D0.y*wr[1] + D0.z*wr[2] + D0.w*wr[3];
            float a1 = D1.x*wr[4] + D1.y*wr[5] + D1.z*wr[6] + D1.w*wr[7];
            float a2 = D2.x*wr[8] + D2.y*wr[9] + D2.z*wr[10] + D2.w*wr[11];
            float a3 = D3.x*wr[12] + D3.y*wr[13] + D3.z*wr[14] + D3.w*wr[15];
            float dot = (a0 + a1) + (a2 + a3);
            float dtv = (dot > 20.f) ? dot : __logf(1.f + __expf(dot));
            float xv  = __bfloat162float(xconv[(rbase + t) * DIN + d]);
            float wt  = __bfloat162float(zw   [(rbase + t) * DIN + d]);
            float u  = dtv * xv;
            float e1 = __expf(-dtv);
            float ep = 1.f;
            dts += dtv;
            #pragma unroll
            for (int s = 0; s < 16; ++s) {
                ep *= e1;
                ap[s] *= ep;
                h[s] = ep * h[s] + u * Bv[s];
                float tc = wt * Cv[s];
                acc += tc * h[s];
                g[s] += tc * ap[s];
            }
            acc += wt * xv * Dval;
        }
    } else {
        for (int t = 0; t < CLEN; ++t) {
            const float* __restrict__ row = dbc + (rbase + t) * 48;   // block-uniform
            float4 D0 = *(const float4*)(row);
            float4 D1 = *(const float4*)(row + 4);
            float4 D2 = *(const float4*)(row + 8);
            float4 D3 = *(const float4*)(row + 12);
            float4 B0 = *(const float4*)(row + 16);
            float4 B1 = *(const float4*)(row + 20);
            float4 B2 = *(const float4*)(row + 24);
            float4 B3 = *(const float4*)(row + 28);
            float4 C0 = *(const float4*)(row + 32);
            float4 C1 = *(const float4*)(row + 36);
            float4 C2 = *(const float4*)(row + 40);
            float4 C3 = *(const float4*)(row + 44);
            float Bv[16], Cv[16];
            *(float4*)&Bv[0] = B0; *(float4*)&Bv[4] = B1; *(float4*)&Bv[8] = B2; *(float4*)&Bv[12] = B3;
            *(float4*)&Cv[0] = C0; *(float4*)&Cv[4] = C1; *(float4*)&Cv[8] = C2; *(float4*)&Cv[12] = C3;
            float a0 = dbias + D0.x*wr[0] + D0.y*wr[1] + D0.z*wr[2] + D0.w*wr[3];
            float a1 = D1.x*wr[4] + D1.y*wr[5] + D1.z*wr[6] + D1.w*wr[7];
            float a2 = D2.x*wr[8] + D2.y*wr[9] + D2.z*wr[10] + D2.w*wr[11];
            float a3 = D3.x*wr[12] + D3.y*wr[13] + D3.z*wr[14] + D3.w*wr[15];
            float dot = (a0 + a1) + (a2 + a3);
            float dtv = (dot > 20.f) ? dot : __logf(1.f + __expf(dot));
            float xv  = __bfloat162float(xconv[(rbase + t) * DIN + d]);
            float wt  = __bfloat162float(zw   [(rbase + t) * DIN + d]);
            float u  = dtv * xv;
            dts += dtv;
            #pragma unroll
            for (int s = 0; s < 16; ++s) {
                float e = __expf(dtv * Aa[s]);
                ap[s] *= e;
                h[s] = e * h[s] + u * Bv[s];
                float tc = wt * Cv[s];
                acc += tc * h[s];
                g[s] += tc * ap[s];
            }
            acc += wt * xv * Dval;
        }
    }
    // s-major coalesced stores: lanes consecutive in d.
    size_t o = (((size_t)b * NCH + c) << 13) + d;
    #pragma unroll
    for (int s = 0; s < 16; ++s) {
        hend[o + (size_t)s * DIN] = h[s];
        Gbuf[o + (size_t)s * DIN] = g[s];
    }
    sumdt [((size_t)b * NCH + c) * DIN + d] = dts;
    accloc[((size_t)b * NCH + c) * DIN + d] = acc;
}

// ---------------------------------------------------------------------------
// Phase 2a: per (b, group of 16 chunks, ds) combine chunks. R12: ds is
// s-major (d = ds&511, s = ds>>9) matching p1's coalesced layout; sumdt
// read is now coalesced too. ap recomputed as exp(A[s]*sumdt).
// grid 2048 x 256.
// ---------------------------------------------------------------------------
__global__ __launch_bounds__(256)
void scan_p2a_kernel(const float* __restrict__ hend,
                     const float* __restrict__ sumdt,
                     const float* __restrict__ Gbuf,
                     const float* __restrict__ accloc,
                     const float* __restrict__ A_log,
                     float* __restrict__ hg, float* __restrict__ Pg,
                     float* __restrict__ Wg, float* __restrict__ part0g,
                     float* __restrict__ accg)
{
    const int g   = blockIdx.x * 256 + threadIdx.x;   // b*65536 + grp*8192 + ds
    const int b   = g >> 16;
    const int grp = (g >> 13) & 7;
    const int ds  = g & 8191;
    const int d   = ds & 511;          // s-major layout
    const int s   = ds >> 9;
    const float Aa = -__expf(A_log[d * DSTATE + s]);
    float h = 0.f, P = 1.f, W = 0.f, p0 = 0.f;
    #pragma unroll
    for (int j = 0; j < NCH / NGRP; ++j) {
        int c = grp * (NCH / NGRP) + j;
        size_t idx = (((size_t)b * NCH + c) << 13) + ds;
        float G  = Gbuf[idx];
        float he = hend[idx];
        float ap = __expf(Aa * sumdt[((size_t)b * NCH + c) * DIN + d]);
        p0 += G * h;
        W  += G * P;
        h   = ap * h + he;
        P  *= ap;
    }
    size_t o = (((size_t)b * NGRP + grp) << 13) + ds;
    hg[o] = h; Pg[o] = P; Wg[o] = W; part0g[o] = p0;
    if (ds < DIN) {
        float a = 0.f;
        #pragma unroll
        for (int j = 0; j < NCH / NGRP; ++j)
            a += accloc[((size_t)b * NCH + grp * (NCH / NGRP) + j) * DIN + ds];
        accg[((size_t)b * NGRP + grp) * DIN + ds] = a;
    }
}

// ---------------------------------------------------------------------------
// Phase 2b: combine 8 groups, reduce over s, write ybar. Thread mapping
// unchanged (shfl over s works: s = ds&15 lane-consecutive); reads remap
// to the s-major buffer layout: off = (ds&15)*DIN + (ds>>4).
// ---------------------------------------------------------------------------
__global__ __launch_bounds__(256)
void scan_p2b_kernel(const float* __restrict__ hg, const float* __restrict__ Pg,
                     const float* __restrict__ Wg, const float* __restrict__ part0g,
                     const float* __restrict__ accg,
                     float* __restrict__ ybar)
{
    const int g  = blockIdx.x * 256 + threadIdx.x;
    const int b  = g >> 13;
    const int ds = g & 8191;
    const int d  = ds >> 4;
    const int s  = ds & 15;
    const int off = s * DIN + d;       // s-major buffer offset
    float h = 0.f, part = 0.f;
    #pragma unroll
    for (int grp = 0; grp < NGRP; ++grp) {
        size_t o = (((size_t)b * NGRP + grp) << 13) + off;
        part += part0g[o] + Wg[o] * h;
        h = Pg[o] * h + hg[o];
    }
    part += __shfl_xor(part, 1, 64);
    part += __shfl_xor(part, 2, 64);
    part += __shfl_xor(part, 4, 64);
    part += __shfl_xor(part, 8, 64);
    if (s == 0) {
        float a = 0.f;
        #pragma unroll
        for (int grp = 0; grp < NGRP; ++grp)
            a += accg[((size_t)b * NGRP + grp) * DIN + d];
        ybar[b * DIN + d] = (part + a) * (1.f / (float)L_);
    }
}

// ---------------------------------------------------------------------------
// Head: one block per batch.
// ---------------------------------------------------------------------------
__global__ __launch_bounds__(256)
void head_kernel(const float* __restrict__ ybar,
                 const float* __restrict__ opw,
                 const float* __restrict__ clsw,
                 const float* __restrict__ clsb,
                 float* __restrict__ out)
{
    __shared__ float pooled_s[H_];
    __shared__ float logit_s[NCLS];
    const int tid = threadIdx.x;
    const int b   = blockIdx.x;
    const float* yb = ybar + b * DIN;
    const float* wr = opw + (size_t)tid * DIN;
    float p = 0.f;
    for (int dd = 0; dd < DIN; dd += 4) {
        float4 y4 = *(const float4*)(yb + dd);
        float4 w4 = *(const float4*)(wr + dd);
        p += y4.x*w4.x + y4.y*w4.y + y4.z*w4.z + y4.w*w4.w;
    }
    pooled_s[tid] = p;
    __syncthreads();
    if (tid < NCLS) {
        float lg = clsb[tid];
        const float* cw = clsw + tid * H_;
        for (int hh = 0; hh < H_; ++hh) lg += pooled_s[hh] * cw[hh];
        logit_s[tid] = lg;
        out[b * NCLS + tid] = lg;
    }
    __syncthreads();
    if (tid == 0) {
        float mx = logit_s[0];
        for (int c = 1; c < NCLS; ++c) mx = fmaxf(mx, logit_s[c]);
        float ssum = 0.f; float e[NCLS];
        for (int c = 0; c < NCLS; ++c) { e[c] = __expf(logit_s[c] - mx); ssum += e[c]; }
        for (int c = 0; c < NCLS; ++c) out[B_*NCLS + b * NCLS + c] = e[c] / ssum;
    }
}

// ---------------------------------------------------------------------------
extern "C" void kernel_launch(void* const* d_in, const int* in_sizes, int n_in,
                              void* d_out, int out_size, void* d_ws, size_t ws_size,
                              hipStream_t stream)
{
    const float* audio    = (const float*)d_in[0];
    const float* visual   = (const float*)d_in[1];
    const float* audio_w  = (const float*)d_in[2];
    const float* audio_b  = (const float*)d_in[3];
    const float* visual_w = (const float*)d_in[4];
    const float* visual_b = (const float*)d_in[5];
    const float* q_w = (const float*)d_in[6];
    const float* q_b = (const float*)d_in[7];
    const float* k_w = (const float*)d_in[8];
    const float* k_b = (const float*)d_in[9];
    const float* v_w = (const float*)d_in[10];
    const float* v_b = (const float*)d_in[11];
    const float* in_proj_w = (const float*)d_in[12];
    const float* conv_w    = (const float*)d_in[13];
    const float* conv_b    = (const float*)d_in[14];
    const float* x_proj_w  = (const float*)d_in[15];
    const float* dt_proj_w = (const float*)d_in[16];
    const float* dt_proj_b = (const float*)d_in[17];
    const float* A_log     = (const float*)d_in[18];
    const float* Dvec      = (const float*)d_in[19];
    const float* out_proj_w= (const float*)d_in[20];
    const float* cls_w     = (const float*)d_in[21];
    const float* cls_b     = (const float*)d_in[22];
    float* out = (float*)d_out;
    float* ws  = (float*)d_ws;

    // ---- workspace (float offsets), peak unchanged (< 33.55M floats) ----
    __hip_bfloat16* abf  = (__hip_bfloat16*)(ws);               // [0, 4.19M)
    __hip_bfloat16* vbf  = (__hip_bfloat16*)(ws + 4194304);     // [4.19M, 8.39M)
    __hip_bfloat16* Qbf  = (__hip_bfloat16*)(ws + 8388608);
    __hip_bfloat16* KVbf = (__hip_bfloat16*)(ws + 10485760);
    __hip_bfloat16* Vt   = (__hip_bfloat16*)(ws + 14680064);
    __hip_bfloat16* fusedbf = (__hip_bfloat16*)(ws + 16777216); // [16.78M, 18.87M)
    __hip_bfloat16* Opart   = (__hip_bfloat16*)(ws + 18874368); // [18.87M, 27.26M)
    __hip_bfloat16* xconvbf = (__hip_bfloat16*)(ws + 27262976); // [27.26M, 31.46M)
    // post-merge reuse:
    __hip_bfloat16* xbufbf = (__hip_bfloat16*)(ws);             // abf region (dead)
    __hip_bfloat16* zwbf   = (__hip_bfloat16*)(ws + 4194304);   // vbf region (dead)
    // scan buffers (NCH=128 layout):
    float* sumdt  = ws;             // [0, 0.52M)        abf region (dead after conv)
    float* accloc = ws + 524288;    // [0.52M, 1.05M)    abf region
    float* hend   = ws + 8388608;   // [8.39M, 16.78M)   Qbf+KVbf+Vt (dead after attn)
    float* Gbuf   = ws + 18874368;  // [18.87M, 27.26M)  Opart (dead after merge)
    float* hg     = ws + 16777216;  // fusedbf region (dead after X/Z)
    float* Pg     = ws + 17301504;
    float* Wgb    = ws + 17825792;
    float* part0g = ws + 18350080;  // ends 18874368
    // small regions:
    __hip_bfloat16* q_wbf   = (__hip_bfloat16*)(ws + 31457280);
    __hip_bfloat16* k_wbf   = (__hip_bfloat16*)(ws + 31490048);
    __hip_bfloat16* v_wbf   = (__hip_bfloat16*)(ws + 31522816);
    __hip_bfloat16* ipwbf   = (__hip_bfloat16*)(ws + 31555584);
    __hip_bfloat16* xpwbf   = (__hip_bfloat16*)(ws + 31686656);
    __hip_bfloat16* awT     = (__hip_bfloat16*)(ws + 31698944);
    __hip_bfloat16* vwT     = (__hip_bfloat16*)(ws + 31764480);
    __hip_bfloat16* Wqp     = (__hip_bfloat16*)(ws + 31830016);
    __hip_bfloat16* Wkvp    = (__hip_bfloat16*)(ws + 31895552);
    float* bq     = ws + 32026624;
    float* bkv    = ws + 32026880;
    float* lpart  = ws + 32027392;   // 65536
    float* dbcb   = ws + 32092928;   // 786432 -> ends 32879360
    float* accg   = ws + 33141504;   // 32768  -> ends 33174272
    float* ybar   = ws + 33174272;   // 4096   -> ends 33178368
    (void)ws_size;

    dim3 blk(256);
    // ---- prep (2 launches, R11: cast+prep fused)
    cast_prep_kernel<<<dim3(9455), blk, 0, stream>>>(audio, visual, abf, vbf,
                                                     q_w, k_w, v_w, in_proj_w, x_proj_w,
                                                     audio_w, visual_w, audio_b, visual_b,
                                                     q_b, k_b, v_b,
                                                     q_wbf, k_wbf, v_wbf, ipwbf, xpwbf,
                                                     awT, vwT, bq, bkv);
    gemm_comp_kernel<<<dim3(16, 8, 3), dim3(64), 0, stream>>>(q_wbf, k_wbf, v_wbf, awT, vwT, Wqp, Wkvp);
    // ---- fused projections (R11: Q+KV in one launch)
    gemm8_qkv_kernel<<<dim3(128, 12), blk, 0, stream>>>(abf, vbf, Wqp, Wkvp, bq, bkv, Qbf, KVbf);
    // ---- attention
    transpose_v_kernel<<<dim3(2048), blk, 0, stream>>>(KVbf, Vt);
    attn_split_kernel<<<dim3(512), blk, 0, stream>>>(Qbf, KVbf, Vt, Opart, lpart);
    attn_merge_kernel<<<dim3(2048), blk, 0, stream>>>(Opart, lpart, fusedbf);
    // ---- mamba in_proj (R11: x+z in one launch)
    gemm8_xz_kernel<<<dim3(128, 16), blk, 0, stream>>>(fusedbf, ipwbf, xbufbf, zwbf);
    conv_silu_kernel<<<dim3(4096), blk, 0, stream>>>(xbufbf, conv_w, conv_b, xconvbf);
    // ---- x_proj (N=48)
    gemm4_t<48, 512, 3, 0, 0><<<dim3(256, 1), blk, 0, stream>>>(xconvbf, xpwbf, nullptr, dbcb);
    // ---- merged chunked scan + two-level combine (p1: NCH=128, grid 2048)
    scan_p1_kernel<<<dim3(2048), blk, 0, stream>>>(xconvbf, zwbf, dbcb, dt_proj_w, dt_proj_b,
                                                   A_log, Dvec, hend, sumdt, Gbuf, accloc);
    scan_p2a_kernel<<<dim3(2048), blk, 0, stream>>>(hend, sumdt, Gbuf, accloc, A_log,
                                                    hg, Pg, Wgb, part0g, accg);
    scan_p2b_kernel<<<dim3(256), blk, 0, stream>>>(hg, Pg, Wgb, part0g, accg, ybar);
    // ---- head
    head_kernel<<<dim3(8), blk, 0, stream>>>(ybar, out_proj_w, cls_w, cls_b, out);
}

// Round 13
// 389.206 us; speedup vs baseline: 1.0731x; 1.0413x over previous
//
#include <hip/hip_runtime.h>
#include <hip/hip_bf16.h>
#include <math.h>

#define B_    8
#define L_    2048
#define AD    512
#define VD    512
#define H_    256
#define DIN   512
#define DSTATE 16
#define DCONV  4
#define DTRANK 16
#define NCLS   8
#define BL    (B_ * L_)   // 16384
#define NCH   128
#define CLEN  16
#define NSP   4
#define NGRP  8           // scan p2 groups (NCH/NGRP = 16 chunks each)

typedef __attribute__((ext_vector_type(8))) short bf16x8;
typedef __attribute__((ext_vector_type(4))) float f32x4;

__device__ inline bf16x8 pack8(float4 a, float4 b)
{
    bf16x8 o; __hip_bfloat16 t;
    t = __float2bfloat16(a.x); o[0] = *(short*)&t;
    t = __float2bfloat16(a.y); o[1] = *(short*)&t;
    t = __float2bfloat16(a.z); o[2] = *(short*)&t;
    t = __float2bfloat16(a.w); o[3] = *(short*)&t;
    t = __float2bfloat16(b.x); o[4] = *(short*)&t;
    t = __float2bfloat16(b.y); o[5] = *(short*)&t;
    t = __float2bfloat16(b.z); o[6] = *(short*)&t;
    t = __float2bfloat16(b.w); o[7] = *(short*)&t;
    return o;
}

// Direct global->LDS DMA, 16B per lane. LDS dest must be wave-uniform base;
// HW writes base + lane*16. Global src is per-lane (enables swizzled layouts).
__device__ __forceinline__ void gload_lds16(const void* g, void* l)
{
    __builtin_amdgcn_global_load_lds(
        (const __attribute__((address_space(1))) void*)g,
        (__attribute__((address_space(3))) void*)l,
        16, 0, 0);
}

// ---------------------------------------------------------------------------
// R11: fused cast_inputs + prep (independent work, one launch).
// blocks [0,8192): input casts. [8192,8428): weight casts.
// [8428,9452): wT transposes. [9452,9455): bias fold.
// ---------------------------------------------------------------------------
__global__ __launch_bounds__(256)
void cast_prep_kernel(const float* __restrict__ a, const float* __restrict__ v,
                      __hip_bfloat16* __restrict__ ab, __hip_bfloat16* __restrict__ vbf_,
                      const float* __restrict__ qw, const float* __restrict__ kw,
                      const float* __restrict__ vw, const float* __restrict__ ipw,
                      const float* __restrict__ xpw,
                      const float* __restrict__ aw, const float* __restrict__ vww,
                      const float* __restrict__ ab2, const float* __restrict__ vb,
                      const float* __restrict__ qb, const float* __restrict__ kb,
                      const float* __restrict__ vb2,
                      __hip_bfloat16* __restrict__ qwb, __hip_bfloat16* __restrict__ kwb,
                      __hip_bfloat16* __restrict__ vwb, __hip_bfloat16* __restrict__ ipwb,
                      __hip_bfloat16* __restrict__ xpwb,
                      __hip_bfloat16* __restrict__ awT, __hip_bfloat16* __restrict__ vwT,
                      float* __restrict__ bq, float* __restrict__ bkv)
{
    const int bx = blockIdx.x;
    if (bx < 8192) {
        size_t i = ((size_t)bx * 256 + threadIdx.x) * 8;
        const float* s; __hip_bfloat16* d; size_t off;
        if (i < 8388608) { s = a; d = ab; off = i; }
        else             { s = v; d = vbf_; off = i - 8388608; }
        float4 x = *(const float4*)(s + off);
        float4 y = *(const float4*)(s + off + 4);
        *(bf16x8*)(d + off) = pack8(x, y);
        return;
    }
    const int blk = bx - 8192;
    if (blk < 236) {
        size_t i = ((size_t)blk * 256 + threadIdx.x) * 8;
        const float* s; __hip_bfloat16* d; size_t off;
        if      (i <  65536) { s = qw;  d = qwb;  off = i; }
        else if (i < 131072) { s = kw;  d = kwb;  off = i - 65536; }
        else if (i < 196608) { s = vw;  d = vwb;  off = i - 131072; }
        else if (i < 458752) { s = ipw; d = ipwb; off = i - 196608; }
        else                 { s = xpw; d = xpwb; off = i - 458752; }
        float4 x = *(const float4*)(s + off);
        float4 y = *(const float4*)(s + off + 4);
        *(bf16x8*)(d + off) = pack8(x, y);
    } else if (blk < 1260) {
        int i = (blk - 236) * 256 + threadIdx.x;       // 0..262143
        const float* s = (i < 131072) ? aw : vww;
        __hip_bfloat16* d = (i < 131072) ? awT : vwT;
        int j = i & 131071;
        int r = j >> 9, c = j & 511;
        d[c * 256 + r] = __float2bfloat16(s[j]);
    } else {
        int seg = blk - 1260;
        int m = threadIdx.x;
        const float* w  = (seg == 0) ? qw : (seg == 1) ? kw : vw;
        const float* ib = (seg == 0) ? ab2 : vb;
        const float* ob = (seg == 0) ? qb : (seg == 1) ? kb : vb2;
        float s = ob[m];
        for (int i = 0; i < 256; ++i) s += w[m * 256 + i] * ib[i];
        if (seg == 0) bq[m] = s;
        else          bkv[(seg - 1) * 256 + m] = s;
    }
}

// ---------------------------------------------------------------------------
// Fused weight-composition GEMMs: z=0: Wq'=q_w@awT; z=1/2: Wk'/Wv'=@vwT.
// 16-row/wave, N=512, K=256, bf16 out. grid (16, 8, 3).
// ---------------------------------------------------------------------------
__global__ __launch_bounds__(64, 2)
void gemm_comp_kernel(const __hip_bfloat16* __restrict__ qw,
                      const __hip_bfloat16* __restrict__ kw,
                      const __hip_bfloat16* __restrict__ vw,
                      const __hip_bfloat16* __restrict__ awT,
                      const __hip_bfloat16* __restrict__ vwT,
                      __hip_bfloat16* __restrict__ Wqp,
                      __hip_bfloat16* __restrict__ Wkvp)
{
    const int seg = blockIdx.z;
    const __hip_bfloat16* A = (seg == 0) ? qw : (seg == 1) ? kw : vw;
    const __hip_bfloat16* W = (seg == 0) ? awT : vwT;
    __hip_bfloat16* outp = (seg == 0) ? Wqp : (Wkvp + (size_t)(seg - 1) * 256 * 512);

    const int lane = threadIdx.x;
    const int l15  = lane & 15;
    const int quad = lane >> 4;
    const int m0   = blockIdx.x * 16;
    const int n0   = blockIdx.y * 64;

    const __hip_bfloat16* Arow = A + (size_t)(m0 + l15) * 256 + quad * 8;
    f32x4 acc[4];
    #pragma unroll
    for (int nt = 0; nt < 4; ++nt) acc[nt] = (f32x4){0.f, 0.f, 0.f, 0.f};

    #pragma unroll
    for (int kc = 0; kc < 256; kc += 32) {
        bf16x8 af = *(const bf16x8*)(Arow + kc);
        #pragma unroll
        for (int nt = 0; nt < 4; ++nt) {
            bf16x8 bfv = *(const bf16x8*)(W + (size_t)(n0 + nt * 16 + l15) * 256 + kc + quad * 8);
            acc[nt] = __builtin_amdgcn_mfma_f32_16x16x32_bf16(af, bfv, acc[nt], 0, 0, 0);
        }
    }
    #pragma unroll
    for (int nt = 0; nt < 4; ++nt) {
        int col = n0 + nt * 16 + l15;
        #pragma unroll
        for (int r = 0; r < 4; ++r)
            outp[(size_t)(m0 + quad * 4 + r) * 512 + col] = __float2bfloat16(acc[nt][r]);
    }
}

// ---------------------------------------------------------------------------
// gemm4_t: 4-wave blocks, 64 rows x NT*16 cols. W staged in LDS (264-pad).
// (kept for xproj N=48)
// ---------------------------------------------------------------------------
template<int N, int K, int NT, int OBF, int ACT>
__global__ __launch_bounds__(256, 2)
void gemm4_t(const __hip_bfloat16* __restrict__ A,
             const __hip_bfloat16* __restrict__ W,
             const float* __restrict__ bias,
             void* __restrict__ outp)
{
    constexpr int NROWS = NT * 16;
    __shared__ __attribute__((aligned(16))) short Ws[NROWS * 264];
    const int tid  = threadIdx.x;
    const int lane = tid & 63;
    const int w    = tid >> 6;
    const int l15  = lane & 15;
    const int quad = lane >> 4;
    const int m0   = blockIdx.x * 64 + w * 16;
    const int n0   = blockIdx.y * 64;

    constexpr int KC = K / 32;
    bf16x8 af[KC];
    const __hip_bfloat16* Arow = A + (size_t)(m0 + l15) * K + quad * 8;
    #pragma unroll
    for (int kc = 0; kc < KC; ++kc) af[kc] = *(const bf16x8*)(Arow + kc * 32);

    f32x4 acc[NT];
    #pragma unroll
    for (int nt = 0; nt < NT; ++nt) acc[nt] = (f32x4){0.f, 0.f, 0.f, 0.f};

    #pragma unroll
    for (int kh = 0; kh < K / 256; ++kh) {
        __syncthreads();
        #pragma unroll
        for (int i = 0; i < 8; ++i) {
            int id = tid + i * 256;
            int row = id >> 5, c = id & 31;
            if (row < NROWS)
                *(bf16x8*)&Ws[row * 264 + c * 8] =
                    *(const bf16x8*)(W + (size_t)(n0 + row) * K + kh * 256 + c * 8);
        }
        __syncthreads();
        #pragma unroll
        for (int kc = 0; kc < 8; ++kc) {
            #pragma unroll
            for (int nt = 0; nt < NT; ++nt) {
                bf16x8 wv = *(const bf16x8*)&Ws[(nt * 16 + l15) * 264 + kc * 32 + quad * 8];
                acc[nt] = __builtin_amdgcn_mfma_f32_16x16x32_bf16(af[kh * 8 + kc], wv, acc[nt], 0, 0, 0);
            }
        }
    }
    #pragma unroll
    for (int nt = 0; nt < NT; ++nt) {
        int col = n0 + nt * 16 + l15;
        float bv = bias ? bias[col] : 0.f;
        #pragma unroll
        for (int r = 0; r < 4; ++r) {
            size_t idx = (size_t)(m0 + quad * 4 + r) * N + col;
            float v = acc[nt][r] + bv;
            if (ACT) v = v / (1.f + __expf(-v));
            if (OBF) ((__hip_bfloat16*)outp)[idx] = __float2bfloat16(v);
            else     ((float*)outp)[idx] = v;
        }
    }
}

// ---------------------------------------------------------------------------
// gemm8 body. R13: W staged via global_load_lds DMA (Common-mistake #1 fix):
// linear LDS dest [64][256], XOR chunk swizzle c^(row&7) applied on the
// GLOBAL source and the read side (rule #21, same involution as attn's K --
// BW-balanced 8 words/bank). Removes 8 ds_write_b128 + addr VALU per thread
// per K-slab; LDS 33.8->32KB. FMA order unchanged -> bitwise-identical.
// ---------------------------------------------------------------------------
template<int K>
__device__ __forceinline__ void gemm8_body(
    const __hip_bfloat16* __restrict__ A,
    const __hip_bfloat16* __restrict__ W,
    const float* __restrict__ bias,
    __hip_bfloat16* __restrict__ outp,
    int N, int n0, int act, short* Ws)
{
    constexpr int NT = 4;
    const int tid  = threadIdx.x;
    const int lane = tid & 63;
    const int w    = tid >> 6;
    const int l15  = lane & 15;
    const int quad = lane >> 4;
    const int m0   = blockIdx.x * 128 + w * 32;
    const int wb   = tid & 192;          // wave-uniform chunk base
    const int sK   = l15 & 7;            // read-side swizzle (row&7; nt*16 is mult of 8)

    f32x4 acc[2][NT];
    #pragma unroll
    for (int s2 = 0; s2 < 2; ++s2)
        #pragma unroll
        for (int nt = 0; nt < NT; ++nt) acc[s2][nt] = (f32x4){0.f, 0.f, 0.f, 0.f};

    #pragma unroll
    for (int kh = 0; kh < K / 256; ++kh) {
        __syncthreads();                 // prev compute done reading Ws
        // DMA-stage W tile (64 rows x 256 sh = 2048 chunks of 16B, 8/thread),
        // source chunk index XOR-swizzled by row&7.
        #pragma unroll
        for (int i = 0; i < 8; ++i) {
            int id  = i * 256 + tid;
            int row = id >> 5, c = id & 31;
            gload_lds16(W + (size_t)(n0 + row) * K + kh * 256 + ((c ^ (row & 7)) << 3),
                        Ws + (i * 256 + wb) * 8);
        }
        // A-frags for this K-slab (independent of staging; latency co-drains).
        bf16x8 af[2][8];
        #pragma unroll
        for (int s2 = 0; s2 < 2; ++s2)
            #pragma unroll
            for (int kc = 0; kc < 8; ++kc)
                af[s2][kc] = *(const bf16x8*)(A + (size_t)(m0 + s2 * 16 + l15) * K
                                              + kh * 256 + kc * 32 + quad * 8);
        __syncthreads();                 // vmcnt(0): W tile + af landed
        #pragma unroll
        for (int kc = 0; kc < 8; ++kc) {
            #pragma unroll
            for (int nt = 0; nt < NT; ++nt) {
                bf16x8 wv = *(const bf16x8*)&Ws[(nt * 16 + l15) * 256 + (((kc * 4 + quad) ^ sK) << 3)];
                acc[0][nt] = __builtin_amdgcn_mfma_f32_16x16x32_bf16(af[0][kc], wv, acc[0][nt], 0, 0, 0);
                acc[1][nt] = __builtin_amdgcn_mfma_f32_16x16x32_bf16(af[1][kc], wv, acc[1][nt], 0, 0, 0);
            }
        }
    }
    #pragma unroll
    for (int s2 = 0; s2 < 2; ++s2)
        #pragma unroll
        for (int nt = 0; nt < NT; ++nt) {
            int col = n0 + nt * 16 + l15;
            float bv = bias ? bias[col] : 0.f;
            #pragma unroll
            for (int r = 0; r < 4; ++r) {
                size_t idx = (size_t)(m0 + s2 * 16 + quad * 4 + r) * N + col;
                float v = acc[s2][nt][r] + bv;
                if (act) v = v / (1.f + __expf(-v));
                outp[idx] = __float2bfloat16(v);
            }
        }
}

// R11: Q + KV projections in ONE launch. grid (128, 12): y<4 -> Q (N=256),
// else KV (N=512). K=512.
__global__ __launch_bounds__(256)
void gemm8_qkv_kernel(const __hip_bfloat16* __restrict__ abf,
                      const __hip_bfloat16* __restrict__ vbf,
                      const __hip_bfloat16* __restrict__ Wqp,
                      const __hip_bfloat16* __restrict__ Wkvp,
                      const float* __restrict__ bq,
                      const float* __restrict__ bkv,
                      __hip_bfloat16* __restrict__ Qbf,
                      __hip_bfloat16* __restrict__ KVbf)
{
    __shared__ __attribute__((aligned(16))) short Ws[64 * 256];
    const int y = blockIdx.y;
    if (y < 4)
        gemm8_body<512>(abf, Wqp,  bq,  Qbf,  256, y * 64,       0, Ws);
    else
        gemm8_body<512>(vbf, Wkvp, bkv, KVbf, 512, (y - 4) * 64, 0, Ws);
}

// R11: in_proj x + z in ONE launch. grid (128, 16): y<8 -> x (ACT=0),
// else z (ACT=1, silu). N=512, K=256.
__global__ __launch_bounds__(256)
void gemm8_xz_kernel(const __hip_bfloat16* __restrict__ fusedbf,
                     const __hip_bfloat16* __restrict__ ipwbf,
                     __hip_bfloat16* __restrict__ xbufbf,
                     __hip_bfloat16* __restrict__ zwbf)
{
    __shared__ __attribute__((aligned(16))) short Ws[64 * 256];
    const int y = blockIdx.y;
    if (y < 8)
        gemm8_body<256>(fusedbf, ipwbf,             nullptr, xbufbf, 512, y * 64,       0, Ws);
    else
        gemm8_body<256>(fusedbf, ipwbf + DIN * H_,  nullptr, zwbf,   512, (y - 8) * 64, 1, Ws);
}

// ---------------------------------------------------------------------------
// V transpose from stacked KV -> Vt[b][h][l]
// ---------------------------------------------------------------------------
__global__ __launch_bounds__(256)
void transpose_v_kernel(const __hip_bfloat16* __restrict__ KV,
                        __hip_bfloat16* __restrict__ Vt)
{
    const int tid = threadIdx.x;
    const int lc  = blockIdx.x & 7;
    const int hg  = (blockIdx.x >> 3) & 31;
    const int b   = blockIdx.x >> 8;
    const int l   = lc * 256 + tid;
    bf16x8 v = *(const bf16x8*)(KV + ((size_t)b * L_ + l) * 512 + 256 + hg * 8);
    __hip_bfloat16* dst = Vt + (size_t)b * H_ * L_ + (size_t)(hg * 8) * L_ + l;
    #pragma unroll
    for (int j = 0; j < 8; ++j) {
        short s = v[j];
        dst[(size_t)j * L_] = *(__hip_bfloat16*)&s;
    }
}

// ---------------------------------------------------------------------------
// Attention: 4 waves/block, 32 queries/WAVE, 128 q/block, 512 keys per split.
// R3: double-buffered LDS K/V staged via global_load_lds DMA (zero VGPR cost,
//     T3 2-phase). XOR chunk swizzle on global source + ds_read side.
// ---------------------------------------------------------------------------
__global__ __launch_bounds__(256, 2)
void attn_split_kernel(const __hip_bfloat16* __restrict__ Q,
                       const __hip_bfloat16* __restrict__ KV,
                       const __hip_bfloat16* __restrict__ Vt,
                       __hip_bfloat16* __restrict__ Opart,
                       float* __restrict__ lpart)
{
    __shared__ __attribute__((aligned(16))) short Ks[2][32 * 256];   // [key][256 sh], swz
    __shared__ __attribute__((aligned(16))) short Vs[2][256 * 32];   // [h][32 sh], swz
    __shared__ __attribute__((aligned(16))) short Pls[4][2][16 * 40];

    const int tid  = threadIdx.x;
    const int lane = tid & 63;
    const int w    = tid >> 6;
    const int b    = blockIdx.x & 7;
    const int qt   = (blockIdx.x >> 3) & 15;
    const int sp   = blockIdx.x >> 7;
    const int q0   = qt * 128 + w * 32;
    const int l15  = lane & 15;
    const int quad = lane >> 4;
    const int wb   = tid & 192;        // wave-uniform chunk base (w*64)

    const __hip_bfloat16* Qb = Q  + ((size_t)b * L_ + q0) * H_;
    const __hip_bfloat16* Kb = KV + (size_t)b * L_ * 512;
    const __hip_bfloat16* Vb = Vt + (size_t)b * H_ * L_;

    bf16x8 qf[2][8];
    #pragma unroll
    for (int s2 = 0; s2 < 2; ++s2)
        #pragma unroll
        for (int kc = 0; kc < 8; ++kc)
            qf[s2][kc] = *(const bf16x8*)(Qb + (size_t)(s2 * 16 + l15) * H_ + kc * 32 + quad * 8);

    f32x4 Oacc[2][16];
    #pragma unroll
    for (int s2 = 0; s2 < 2; ++s2)
        #pragma unroll
        for (int nt = 0; nt < 16; ++nt) Oacc[s2][nt] = (f32x4){0.f, 0.f, 0.f, 0.f};
    float lsum[2][4] = {{0.f,0.f,0.f,0.f},{0.f,0.f,0.f,0.f}};

    const int kbase = sp * 512;
    const int sK = l15 & 7;                       // K read swizzle (row&7)
    const int vcol8 = (quad ^ (l15 & 3)) * 8;     // V read swizzle (row&3)

    // DMA staging: 1024 chunks of 16B each for K and V per tile.
#define STAGE(KsD, VsD, stv) do {                                                 \
        const int kb_ = kbase + (stv) * 32;                                       \
        _Pragma("unroll")                                                         \
        for (int i_ = 0; i_ < 4; ++i_) {                                          \
            int q_ = i_ * 256 + tid;                                              \
            int rK_ = q_ >> 5, cK_ = q_ & 31;                                     \
            gload_lds16(Kb + (size_t)(kb_ + rK_) * 512 + ((cK_ ^ (rK_ & 7)) << 3),\
                        (KsD) + (i_ * 256 + wb) * 8);                             \
            int rV_ = q_ >> 2, cV_ = q_ & 3;                                      \
            gload_lds16(Vb + (size_t)rV_ * L_ + kb_ + ((cV_ ^ (rV_ & 3)) << 3),   \
                        (VsD) + (i_ * 256 + wb) * 8);                             \
        }                                                                         \
    } while (0)

    STAGE(Ks[0], Vs[0], 0);
    __syncthreads();                               // vmcnt(0): tile 0 landed
    for (int st = 0; st < 16; ++st) {
        const int cur = st & 1;
        short* KsC = Ks[cur];
        short* VsC = Vs[cur];
        if (st < 15) STAGE(Ks[cur ^ 1], Vs[cur ^ 1], st + 1);  // async, drains at bottom barrier
        // ---- S = Q K^T : each K-frag feeds both q-sets
        #pragma unroll
        for (int nt = 0; nt < 2; ++nt) {
            f32x4 S0 = (f32x4){0.f,0.f,0.f,0.f};
            f32x4 S1 = (f32x4){0.f,0.f,0.f,0.f};
            __builtin_amdgcn_s_setprio(1);
            #pragma unroll
            for (int kc = 0; kc < 8; ++kc) {
                bf16x8 bk = *(const bf16x8*)&KsC[(nt * 16 + l15) * 256 + (((kc * 4 + quad) ^ sK) << 3)];
                S0 = __builtin_amdgcn_mfma_f32_16x16x32_bf16(qf[0][kc], bk, S0, 0, 0, 0);
                S1 = __builtin_amdgcn_mfma_f32_16x16x32_bf16(qf[1][kc], bk, S1, 0, 0, 0);
            }
            __builtin_amdgcn_s_setprio(0);
            #pragma unroll
            for (int r = 0; r < 4; ++r) {
                float p0 = __expf(S0[r] * 0.0625f);
                float p1 = __expf(S1[r] * 0.0625f);
                lsum[0][r] += p0;
                lsum[1][r] += p1;
                __hip_bfloat16 pb0 = __float2bfloat16(p0);
                __hip_bfloat16 pb1 = __float2bfloat16(p1);
                Pls[w][0][(quad * 4 + r) * 40 + nt * 16 + l15] = *(short*)&pb0;
                Pls[w][1][(quad * 4 + r) * 40 + nt * 16 + l15] = *(short*)&pb1;
            }
        }
        bf16x8 pf0 = *(const bf16x8*)&Pls[w][0][l15 * 40 + quad * 8];
        bf16x8 pf1 = *(const bf16x8*)&Pls[w][1][l15 * 40 + quad * 8];
        // ---- O += P V : each V-frag feeds both q-sets
        __builtin_amdgcn_s_setprio(1);
        #pragma unroll
        for (int nt = 0; nt < 16; ++nt) {
            bf16x8 vf = *(const bf16x8*)&VsC[(nt * 16 + l15) * 32 + vcol8];
            Oacc[0][nt] = __builtin_amdgcn_mfma_f32_16x16x32_bf16(pf0, vf, Oacc[0][nt], 0, 0, 0);
            Oacc[1][nt] = __builtin_amdgcn_mfma_f32_16x16x32_bf16(pf1, vf, Oacc[1][nt], 0, 0, 0);
        }
        __builtin_amdgcn_s_setprio(0);
        __syncthreads();    // compute(cur) done + next tile's DMA drained (vmcnt 0)
    }
#undef STAGE
    #pragma unroll
    for (int s2 = 0; s2 < 2; ++s2)
        #pragma unroll
        for (int r = 0; r < 4; ++r) {
            lsum[s2][r] += __shfl_xor(lsum[s2][r], 1, 64);
            lsum[s2][r] += __shfl_xor(lsum[s2][r], 2, 64);
            lsum[s2][r] += __shfl_xor(lsum[s2][r], 4, 64);
            lsum[s2][r] += __shfl_xor(lsum[s2][r], 8, 64);
        }
    __hip_bfloat16* Ob = Opart + (((size_t)sp * B_ + b) * L_ + q0) * H_;
    #pragma unroll
    for (int s2 = 0; s2 < 2; ++s2)
        #pragma unroll
        for (int r = 0; r < 4; ++r)
            #pragma unroll
            for (int nt = 0; nt < 16; ++nt)
                Ob[(size_t)(s2 * 16 + quad * 4 + r) * H_ + nt * 16 + l15] =
                    __float2bfloat16(Oacc[s2][nt][r]);
    if (l15 == 0) {
        #pragma unroll
        for (int s2 = 0; s2 < 2; ++s2)
            #pragma unroll
            for (int r = 0; r < 4; ++r)
                lpart[((size_t)sp * B_ + b) * L_ + q0 + s2 * 16 + quad * 4 + r] = lsum[s2][r];
    }
}

// ---------------------------------------------------------------------------
// Merge attention splits. R7: bf16x8-vectorized. grid 2048.
// ---------------------------------------------------------------------------
__global__ __launch_bounds__(256)
void attn_merge_kernel(const __hip_bfloat16* __restrict__ Opart,
                       const float* __restrict__ lpart,
                       __hip_bfloat16* __restrict__ O)
{
    const size_t i8  = ((size_t)blockIdx.x * 256 + threadIdx.x) * 8;
    const size_t row = i8 >> 8;
    float l = 0.f;
    #pragma unroll
    for (int sp = 0; sp < NSP; ++sp) l += lpart[(size_t)sp * BL + row];
    const float inv = 1.f / l;
    float o[8] = {0.f,0.f,0.f,0.f,0.f,0.f,0.f,0.f};
    #pragma unroll
    for (int sp = 0; sp < NSP; ++sp) {
        bf16x8 v = *(const bf16x8*)(Opart + (size_t)sp * BL * H_ + i8);
        #pragma unroll
        for (int j = 0; j < 8; ++j) {
            short s = v[j];
            o[j] += __bfloat162float(*(__hip_bfloat16*)&s);
        }
    }
    bf16x8 ov;
    #pragma unroll
    for (int j = 0; j < 8; ++j) {
        __hip_bfloat16 t = __float2bfloat16(o[j] * inv);
        ov[j] = *(short*)&t;
    }
    *(bf16x8*)(O + i8) = ov;
}

// ---------------------------------------------------------------------------
// Depthwise causal conv (k=4) + bias + silu: bf16 in, bf16 out.
// R7: 8 channels/thread, bf16x8 tap loads + bf16x8 store. grid 4096.
// ---------------------------------------------------------------------------
__global__ __launch_bounds__(256)
void conv_silu_kernel(const __hip_bfloat16* __restrict__ xb,
                      const float* __restrict__ cw,
                      const float* __restrict__ cb,
                      __hip_bfloat16* __restrict__ xconvbf)
{
    const int idx = blockIdx.x * 256 + threadIdx.x;   // [0, BL*DIN/8)
    const int d0 = (idx & 63) << 3;
    const int l  = (idx >> 6) & (L_ - 1);
    const int b  = idx >> 17;

    float4 wv[8];
    float acc[8];
    #pragma unroll
    for (int j = 0; j < 8; ++j) {
        wv[j]  = *(const float4*)(cw + (d0 + j) * DCONV);
        acc[j] = cb[d0 + j];
    }
    #pragma unroll
    for (int t = 0; t < DCONV; ++t) {
        int ls = l - (DCONV - 1) + t;
        if (ls >= 0) {
            bf16x8 x = *(const bf16x8*)(xb + ((size_t)b * L_ + ls) * DIN + d0);
            #pragma unroll
            for (int j = 0; j < 8; ++j) {
                short s = x[j];
                float xv = __bfloat162float(*(__hip_bfloat16*)&s);
                float wt = (t == 0) ? wv[j].x : (t == 1) ? wv[j].y : (t == 2) ? wv[j].z : wv[j].w;
                acc[j] += xv * wt;
            }
        }
    }
    bf16x8 ov;
    #pragma unroll
    for (int j = 0; j < 8; ++j) {
        float v = acc[j] / (1.f + __expf(-acc[j]));
        __hip_bfloat16 t = __float2bfloat16(v);
        ov[j] = *(short*)&t;
    }
    *(bf16x8*)(xconvbf + (size_t)idx * 8) = ov;
}

// ---------------------------------------------------------------------------
// Merged scan phase 1. R12: s-major coalesced state stores; R9 uniform
// s_loads for dbc; NCH=128/CLEN=16 + sumdt.
// ---------------------------------------------------------------------------
__global__ __launch_bounds__(256)
void scan_p1_kernel(const __hip_bfloat16* __restrict__ xconv,
                    const __hip_bfloat16* __restrict__ zw,
                    const float* __restrict__ dbc,
                    const float* __restrict__ dtw,
                    const float* __restrict__ dtbias,
                    const float* __restrict__ A_log,
                    const float* __restrict__ Dv,
                    float* __restrict__ hend,
                    float* __restrict__ sumdt,
                    float* __restrict__ Gbuf,
                    float* __restrict__ accloc)
{
    const int tid  = threadIdx.x;
    const int dgrp = blockIdx.x & 1;
    const int c    = (blockIdx.x >> 1) & (NCH - 1);
    const int b    = blockIdx.x >> 8;
    const int d    = dgrp * 256 + tid;
    const size_t rbase = (size_t)b * L_ + c * CLEN;

    float wr[16];
    #pragma unroll
    for (int r = 0; r < 16; ++r) wr[r] = dtw[d * DTRANK + r];
    const float dbias = dtbias[d];
    const float Dval  = Dv[d];

    float Aa[16];
    bool fast = true;
    #pragma unroll
    for (int s = 0; s < 16; ++s) {
        Aa[s] = -__expf(A_log[d * DSTATE + s]);
        fast = fast && (fabsf(Aa[s] + (float)(s + 1)) < 1e-3f);
    }

    float h[16], ap[16], g[16];
    #pragma unroll
    for (int s = 0; s < 16; ++s) { h[s] = 0.f; ap[s] = 1.f; g[s] = 0.f; }
    float acc = 0.f;
    float dts = 0.f;

    if (fast) {
        for (int t = 0; t < CLEN; ++t) {
            const float* __restrict__ row = dbc + (rbase + t) * 48;   // block-uniform
            float4 D0 = *(const float4*)(row);
            float4 D1 = *(const float4*)(row + 4);
            float4 D2 = *(const float4*)(row + 8);
            float4 D3 = *(const float4*)(row + 12);
            float4 B0 = *(const float4*)(row + 16);
            float4 B1 = *(const float4*)(row + 20);
            float4 B2 = *(const float4*)(row + 24);
            float4 B3 = *(const float4*)(row + 28);
            float4 C0 = *(const float4*)(row + 32);
            float4 C1 = *(const float4*)(row + 36);
            float4 C2 = *(const float4*)(row + 40);
            float4 C3 = *(const float4*)(row + 44);
            float Bv[16], Cv[16];
            *(float4*)&Bv[0] = B0; *(float4*)&Bv[4] = B1; *(float4*)&Bv[8] = B2; *(float4*)&Bv[12] = B3;
            *(float4*)&Cv[0] = C0; *(float4*)&Cv[4] = C1; *(float4*)&Cv[8] = C2; *(float4*)&Cv[12] = C3;
            float a0 = dbias + D0.x*wr[0] + D0.y*wr[1] + D0.z*wr[2] + D0.w*wr[3];
            float a1 = D1.x*wr[4] + D1.y*wr[5] + D1.z*wr[6] + D1.w*wr[7];
            float a2 = D2.x*wr[8] + D2.y*wr[9] + D2.z*wr[10] + D2.w*wr[11];
            float a3 = D3.x*wr[12] + D3.y*wr[13] + D3.z*wr[14] + D3.w*wr[15];
            float dot = (a0 + a1) + (a2 + a3);
            float dtv = (dot > 20.f) ? dot : __logf(1.f + __expf(dot));
            float xv  = __bfloat162float(xconv[(rbase + t) * DIN + d]);
            float wt  = __bfloat162float(zw   [(rbase + t) * DIN + d]);
            float u  = dtv * xv;
            float e1 = __expf(-dtv);
            float ep = 1.f;
            dts += dtv;
            #pragma unroll
            for (int s = 0; s < 16; ++s) {
                ep *= e1;
                ap[s] *= ep;
                h[s] = ep * h[s] + u * Bv[s];
                float tc = wt * Cv[s];
                acc += tc * h[s];
                g[s] += tc * ap[s];
            }
            acc += wt * xv * Dval;
        }
    } else {
        for (int t = 0; t < CLEN; ++t) {
            const float* __restrict__ row = dbc + (rbase + t) * 48;   // block-uniform
            float4 D0 = *(const float4*)(row);
            float4 D1 = *(const float4*)(row + 4);
            float4 D2 = *(const float4*)(row + 8);
            float4 D3 = *(const float4*)(row + 12);
            float4 B0 = *(const float4*)(row + 16);
            float4 B1 = *(const float4*)(row + 20);
            float4 B2 = *(const float4*)(row + 24);
            float4 B3 = *(const float4*)(row + 28);
            float4 C0 = *(const float4*)(row + 32);
            float4 C1 = *(const float4*)(row + 36);
            float4 C2 = *(const float4*)(row + 40);
            float4 C3 = *(const float4*)(row + 44);
            float Bv[16], Cv[16];
            *(float4*)&Bv[0] = B0; *(float4*)&Bv[4] = B1; *(float4*)&Bv[8] = B2; *(float4*)&Bv[12] = B3;
            *(float4*)&Cv[0] = C0; *(float4*)&Cv[4] = C1; *(float4*)&Cv[8] = C2; *(float4*)&Cv[12] = C3;
            float a0 = dbias + D0.x*wr[0] + D0.y*wr[1] + D0.z*wr[2] + D0.w*wr[3];
            float a1 = D1.x*wr[4] + D1.y*wr[5] + D1.z*wr[6] + D1.w*wr[7];
            float a2 = D2.x*wr[8] + D2.y*wr[9] + D2.z*wr[10] + D2.w*wr[11];
            float a3 = D3.x*wr[12] + D3.y*wr[13] + D3.z*wr[14] + D3.w*wr[15];
            float dot = (a0 + a1) + (a2 + a3);
            float dtv = (dot > 20.f) ? dot : __logf(1.f + __expf(dot));
            float xv  = __bfloat162float(xconv[(rbase + t) * DIN + d]);
            float wt  = __bfloat162float(zw   [(rbase + t) * DIN + d]);
            float u  = dtv * xv;
            dts += dtv;
            #pragma unroll
            for (int s = 0; s < 16; ++s) {
                float e = __expf(dtv * Aa[s]);
                ap[s] *= e;
                h[s] = e * h[s] + u * Bv[s];
                float tc = wt * Cv[s];
                acc += tc * h[s];
                g[s] += tc * ap[s];
            }
            acc += wt * xv * Dval;
        }
    }
    // s-major coalesced stores: lanes consecutive in d.
    size_t o = (((size_t)b * NCH + c) << 13) + d;
    #pragma unroll
    for (int s = 0; s < 16; ++s) {
        hend[o + (size_t)s * DIN] = h[s];
        Gbuf[o + (size_t)s * DIN] = g[s];
    }
    sumdt [((size_t)b * NCH + c) * DIN + d] = dts;
    accloc[((size_t)b * NCH + c) * DIN + d] = acc;
}

// ---------------------------------------------------------------------------
// Phase 2a: per (b, group of 16 chunks, ds) combine chunks. R12: ds is
// s-major (d = ds&511, s = ds>>9). ap recomputed as exp(A[s]*sumdt).
// grid 2048 x 256.
// ---------------------------------------------------------------------------
__global__ __launch_bounds__(256)
void scan_p2a_kernel(const float* __restrict__ hend,
                     const float* __restrict__ sumdt,
                     const float* __restrict__ Gbuf,
                     const float* __restrict__ accloc,
                     const float* __restrict__ A_log,
                     float* __restrict__ hg, float* __restrict__ Pg,
                     float* __restrict__ Wg, float* __restrict__ part0g,
                     float* __restrict__ accg)
{
    const int g   = blockIdx.x * 256 + threadIdx.x;   // b*65536 + grp*8192 + ds
    const int b   = g >> 16;
    const int grp = (g >> 13) & 7;
    const int ds  = g & 8191;
    const int d   = ds & 511;          // s-major layout
    const int s   = ds >> 9;
    const float Aa = -__expf(A_log[d * DSTATE + s]);
    float h = 0.f, P = 1.f, W = 0.f, p0 = 0.f;
    #pragma unroll
    for (int j = 0; j < NCH / NGRP; ++j) {
        int c = grp * (NCH / NGRP) + j;
        size_t idx = (((size_t)b * NCH + c) << 13) + ds;
        float G  = Gbuf[idx];
        float he = hend[idx];
        float ap = __expf(Aa * sumdt[((size_t)b * NCH + c) * DIN + d]);
        p0 += G * h;
        W  += G * P;
        h   = ap * h + he;
        P  *= ap;
    }
    size_t o = (((size_t)b * NGRP + grp) << 13) + ds;
    hg[o] = h; Pg[o] = P; Wg[o] = W; part0g[o] = p0;
    if (ds < DIN) {
        float a = 0.f;
        #pragma unroll
        for (int j = 0; j < NCH / NGRP; ++j)
            a += accloc[((size_t)b * NCH + grp * (NCH / NGRP) + j) * DIN + ds];
        accg[((size_t)b * NGRP + grp) * DIN + ds] = a;
    }
}

// ---------------------------------------------------------------------------
// Phase 2b: combine 8 groups, reduce over s, write ybar. Reads remap to
// the s-major buffer layout: off = (ds&15)*DIN + (ds>>4).
// ---------------------------------------------------------------------------
__global__ __launch_bounds__(256)
void scan_p2b_kernel(const float* __restrict__ hg, const float* __restrict__ Pg,
                     const float* __restrict__ Wg, const float* __restrict__ part0g,
                     const float* __restrict__ accg,
                     float* __restrict__ ybar)
{
    const int g  = blockIdx.x * 256 + threadIdx.x;
    const int b  = g >> 13;
    const int ds = g & 8191;
    const int d  = ds >> 4;
    const int s  = ds & 15;
    const int off = s * DIN + d;       // s-major buffer offset
    float h = 0.f, part = 0.f;
    #pragma unroll
    for (int grp = 0; grp < NGRP; ++grp) {
        size_t o = (((size_t)b * NGRP + grp) << 13) + off;
        part += part0g[o] + Wg[o] * h;
        h = Pg[o] * h + hg[o];
    }
    part += __shfl_xor(part, 1, 64);
    part += __shfl_xor(part, 2, 64);
    part += __shfl_xor(part, 4, 64);
    part += __shfl_xor(part, 8, 64);
    if (s == 0) {
        float a = 0.f;
        #pragma unroll
        for (int grp = 0; grp < NGRP; ++grp)
            a += accg[((size_t)b * NGRP + grp) * DIN + d];
        ybar[b * DIN + d] = (part + a) * (1.f / (float)L_);
    }
}

// ---------------------------------------------------------------------------
// Head: one block per batch.
// ---------------------------------------------------------------------------
__global__ __launch_bounds__(256)
void head_kernel(const float* __restrict__ ybar,
                 const float* __restrict__ opw,
                 const float* __restrict__ clsw,
                 const float* __restrict__ clsb,
                 float* __restrict__ out)
{
    __shared__ float pooled_s[H_];
    __shared__ float logit_s[NCLS];
    const int tid = threadIdx.x;
    const int b   = blockIdx.x;
    const float* yb = ybar + b * DIN;
    const float* wr = opw + (size_t)tid * DIN;
    float p = 0.f;
    for (int dd = 0; dd < DIN; dd += 4) {
        float4 y4 = *(const float4*)(yb + dd);
        float4 w4 = *(const float4*)(wr + dd);
        p += y4.x*w4.x + y4.y*w4.y + y4.z*w4.z + y4.w*w4.w;
    }
    pooled_s[tid] = p;
    __syncthreads();
    if (tid < NCLS) {
        float lg = clsb[tid];
        const float* cw = clsw + tid * H_;
        for (int hh = 0; hh < H_; ++hh) lg += pooled_s[hh] * cw[hh];
        logit_s[tid] = lg;
        out[b * NCLS + tid] = lg;
    }
    __syncthreads();
    if (tid == 0) {
        float mx = logit_s[0];
        for (int c = 1; c < NCLS; ++c) mx = fmaxf(mx, logit_s[c]);
        float ssum = 0.f; float e[NCLS];
        for (int c = 0; c < NCLS; ++c) { e[c] = __expf(logit_s[c] - mx); ssum += e[c]; }
        for (int c = 0; c < NCLS; ++c) out[B_*NCLS + b * NCLS + c] = e[c] / ssum;
    }
}

// ---------------------------------------------------------------------------
extern "C" void kernel_launch(void* const* d_in, const int* in_sizes, int n_in,
                              void* d_out, int out_size, void* d_ws, size_t ws_size,
                              hipStream_t stream)
{
    const float* audio    = (const float*)d_in[0];
    const float* visual   = (const float*)d_in[1];
    const float* audio_w  = (const float*)d_in[2];
    const float* audio_b  = (const float*)d_in[3];
    const float* visual_w = (const float*)d_in[4];
    const float* visual_b = (const float*)d_in[5];
    const float* q_w = (const float*)d_in[6];
    const float* q_b = (const float*)d_in[7];
    const float* k_w = (const float*)d_in[8];
    const float* k_b = (const float*)d_in[9];
    const float* v_w = (const float*)d_in[10];
    const float* v_b = (const float*)d_in[11];
    const float* in_proj_w = (const float*)d_in[12];
    const float* conv_w    = (const float*)d_in[13];
    const float* conv_b    = (const float*)d_in[14];
    const float* x_proj_w  = (const float*)d_in[15];
    const float* dt_proj_w = (const float*)d_in[16];
    const float* dt_proj_b = (const float*)d_in[17];
    const float* A_log     = (const float*)d_in[18];
    const float* Dvec      = (const float*)d_in[19];
    const float* out_proj_w= (const float*)d_in[20];
    const float* cls_w     = (const float*)d_in[21];
    const float* cls_b     = (const float*)d_in[22];
    float* out = (float*)d_out;
    float* ws  = (float*)d_ws;

    // ---- workspace (float offsets), peak unchanged (< 33.55M floats) ----
    __hip_bfloat16* abf  = (__hip_bfloat16*)(ws);               // [0, 4.19M)
    __hip_bfloat16* vbf  = (__hip_bfloat16*)(ws + 4194304);     // [4.19M, 8.39M)
    __hip_bfloat16* Qbf  = (__hip_bfloat16*)(ws + 8388608);
    __hip_bfloat16* KVbf = (__hip_bfloat16*)(ws + 10485760);
    __hip_bfloat16* Vt   = (__hip_bfloat16*)(ws + 14680064);
    __hip_bfloat16* fusedbf = (__hip_bfloat16*)(ws + 16777216); // [16.78M, 18.87M)
    __hip_bfloat16* Opart   = (__hip_bfloat16*)(ws + 18874368); // [18.87M, 27.26M)
    __hip_bfloat16* xconvbf = (__hip_bfloat16*)(ws + 27262976); // [27.26M, 31.46M)
    // post-merge reuse:
    __hip_bfloat16* xbufbf = (__hip_bfloat16*)(ws);             // abf region (dead)
    __hip_bfloat16* zwbf   = (__hip_bfloat16*)(ws + 4194304);   // vbf region (dead)
    // scan buffers (NCH=128 layout):
    float* sumdt  = ws;             // [0, 0.52M)        abf region (dead after conv)
    float* accloc = ws + 524288;    // [0.52M, 1.05M)    abf region
    float* hend   = ws + 8388608;   // [8.39M, 16.78M)   Qbf+KVbf+Vt (dead after attn)
    float* Gbuf   = ws + 18874368;  // [18.87M, 27.26M)  Opart (dead after merge)
    float* hg     = ws + 16777216;  // fusedbf region (dead after X/Z)
    float* Pg     = ws + 17301504;
    float* Wgb    = ws + 17825792;
    float* part0g = ws + 18350080;  // ends 18874368
    // small regions:
    __hip_bfloat16* q_wbf   = (__hip_bfloat16*)(ws + 31457280);
    __hip_bfloat16* k_wbf   = (__hip_bfloat16*)(ws + 31490048);
    __hip_bfloat16* v_wbf   = (__hip_bfloat16*)(ws + 31522816);
    __hip_bfloat16* ipwbf   = (__hip_bfloat16*)(ws + 31555584);
    __hip_bfloat16* xpwbf   = (__hip_bfloat16*)(ws + 31686656);
    __hip_bfloat16* awT     = (__hip_bfloat16*)(ws + 31698944);
    __hip_bfloat16* vwT     = (__hip_bfloat16*)(ws + 31764480);
    __hip_bfloat16* Wqp     = (__hip_bfloat16*)(ws + 31830016);
    __hip_bfloat16* Wkvp    = (__hip_bfloat16*)(ws + 31895552);
    float* bq     = ws + 32026624;
    float* bkv    = ws + 32026880;
    float* lpart  = ws + 32027392;   // 65536
    float* dbcb   = ws + 32092928;   // 786432 -> ends 32879360
    float* accg   = ws + 33141504;   // 32768  -> ends 33174272
    float* ybar   = ws + 33174272;   // 4096   -> ends 33178368
    (void)ws_size;

    dim3 blk(256);
    // ---- prep (2 launches, R11: cast+prep fused)
    cast_prep_kernel<<<dim3(9455), blk, 0, stream>>>(audio, visual, abf, vbf,
                                                     q_w, k_w, v_w, in_proj_w, x_proj_w,
                                                     audio_w, visual_w, audio_b, visual_b,
                                                     q_b, k_b, v_b,
                                                     q_wbf, k_wbf, v_wbf, ipwbf, xpwbf,
                                                     awT, vwT, bq, bkv);
    gemm_comp_kernel<<<dim3(16, 8, 3), dim3(64), 0, stream>>>(q_wbf, k_wbf, v_wbf, awT, vwT, Wqp, Wkvp);
    // ---- fused projections (R13: DMA-staged gemm8)
    gemm8_qkv_kernel<<<dim3(128, 12), blk, 0, stream>>>(abf, vbf, Wqp, Wkvp, bq, bkv, Qbf, KVbf);
    // ---- attention
    transpose_v_kernel<<<dim3(2048), blk, 0, stream>>>(KVbf, Vt);
    attn_split_kernel<<<dim3(512), blk, 0, stream>>>(Qbf, KVbf, Vt, Opart, lpart);
    attn_merge_kernel<<<dim3(2048), blk, 0, stream>>>(Opart, lpart, fusedbf);
    // ---- mamba in_proj (R13: DMA-staged gemm8)
    gemm8_xz_kernel<<<dim3(128, 16), blk, 0, stream>>>(fusedbf, ipwbf, xbufbf, zwbf);
    conv_silu_kernel<<<dim3(4096), blk, 0, stream>>>(xbufbf, conv_w, conv_b, xconvbf);
    // ---- x_proj (N=48)
    gemm4_t<48, 512, 3, 0, 0><<<dim3(256, 1), blk, 0, stream>>>(xconvbf, xpwbf, nullptr, dbcb);
    // ---- merged chunked scan + two-level combine (p1: NCH=128, grid 2048)
    scan_p1_kernel<<<dim3(2048), blk, 0, stream>>>(xconvbf, zwbf, dbcb, dt_proj_w, dt_proj_b,
                                                   A_log, Dvec, hend, sumdt, Gbuf, accloc);
    scan_p2a_kernel<<<dim3(2048), blk, 0, stream>>>(hend, sumdt, Gbuf, accloc, A_log,
                                                    hg, Pg, Wgb, part0g, accg);
    scan_p2b_kernel<<<dim3(256), blk, 0, stream>>>(hg, Pg, Wgb, part0g, accg, ybar);
    // ---- head
    head_kernel<<<dim3(8), blk, 0, stream>>>(ybar, out_proj_w, cls_w, cls_b, out);
}